// Round 2
// baseline (9707.396 us; speedup 1.0000x reference)
//
#include <hip/hip_runtime.h>
#include <hip/hip_bf16.h>
#include <stdint.h>

typedef unsigned short u16;
typedef unsigned int   u32;

// ---------- bf16 helpers (storage-only bf16, f32 math) ----------
__device__ __forceinline__ float bf2f(u16 a) {
  union { u32 i; float f; } t; t.i = ((u32)a) << 16; return t.f;
}
__device__ __forceinline__ u16 f2bf(float f) {
  union { u32 i; float f; } t; t.f = f;
  u32 r = t.i + 0x7fffu + ((t.i >> 16) & 1u);   // round-nearest-even
  return (u16)(r >> 16);
}
__device__ __forceinline__ u32 pack2(float a, float b) {
  return (u32)f2bf(a) | ((u32)f2bf(b) << 16);
}
__device__ __forceinline__ void unpack8(uint4 u, float* o) {
  union { u32 i; float f; } t;
  t.i = u.x << 16;         o[0] = t.f;
  t.i = u.x & 0xffff0000u; o[1] = t.f;
  t.i = u.y << 16;         o[2] = t.f;
  t.i = u.y & 0xffff0000u; o[3] = t.f;
  t.i = u.z << 16;         o[4] = t.f;
  t.i = u.z & 0xffff0000u; o[5] = t.f;
  t.i = u.w << 16;         o[6] = t.f;
  t.i = u.w & 0xffff0000u; o[7] = t.f;
}

#define NB 4
#define NN 4600
#define FF 5
#define PP 920
#define CC 512

// ---------- generic 64x64 f32 tiled GEMM (A via provider, C via sink) ----------
struct AProvX {        // A row r=(b,n) -> x[n,b,c]   (f32 input)
  const float* x;
  __device__ __forceinline__ float ld(int r, int k) const {
    int b = r / NN, n = r - b * NN;
    return x[((size_t)n * NB + b) * CC + k];
  }
};
struct AProvBF {       // contiguous bf16 rows, stride 512
  const u16* a;
  __device__ __forceinline__ float ld(int r, int k) const {
    return bf2f(a[(size_t)r * CC + k]);
  }
};
struct AProvDiag {     // x_diag: row (b,n) -> xo[b,n, n/P, c]
  const u16* xo;
  __device__ __forceinline__ float ld(int r, int k) const {
    int b = r / NN, n = r - b * NN;
    int f = n / PP;
    return bf2f(xo[(((size_t)b * NN + n) * FF + f) * CC + k]);
  }
};
struct CSinkQKV {      // split 1536 cols into q/k/v bf16
  u16 *q, *k, *v;
  __device__ __forceinline__ void st(int r, int c, float val) const {
    u16 h = f2bf(val);
    if (c < 512)        q[(size_t)r * CC + c] = h;
    else if (c < 1024)  k[(size_t)r * CC + (c - 512)] = h;
    else                v[(size_t)r * CC + (c - 1024)] = h;
  }
};
struct CSinkQ2 {       // bf16 * scale (dh^-0.5 = 0.125)
  u16* o;
  __device__ __forceinline__ void st(int r, int c, float v) const {
    o[(size_t)r * CC + c] = f2bf(v * 0.125f);
  }
};
struct CSinkProj {     // + bias, scatter to (P, B*F, C) f32
  float* out; const float* bias;
  __device__ __forceinline__ void st(int r, int c, float v) const {
    int b = r / NN, rem = r - b * NN;
    int f = rem / PP, p = rem - f * PP;
    out[((size_t)p * (NB * FF) + b * FF + f) * CC + c] = v + bias[c];
  }
};

template<class AP, class CS>
__global__ __launch_bounds__(256) void gemm64(AP ap, const float* __restrict__ Bm,
                                              CS cs, int M, int K, int Nc) {
  __shared__ __align__(16) float As[16][68];   // [k][row], padded
  __shared__ __align__(16) float Bs[16][68];   // [k][col], padded
  const int tid = threadIdx.x;
  const int tx = tid & 15, ty = tid >> 4;
  const int row0 = blockIdx.y * 64, col0 = blockIdx.x * 64;
  float acc[4][4] = {};
  for (int k0 = 0; k0 < K; k0 += 16) {
    __syncthreads();
    #pragma unroll
    for (int i = 0; i < 4; i++) {            // A tile 64x16
      int idx = tid + i * 256;
      int ak = idx & 15, ar = idx >> 4;
      int r = row0 + ar;
      As[ak][ar] = (r < M) ? ap.ld(r, k0 + ak) : 0.f;
    }
    #pragma unroll
    for (int i = 0; i < 4; i++) {            // B tile 16x64
      int idx = tid + i * 256;
      int bk = idx >> 6, bc = idx & 63;
      Bs[bk][bc] = Bm[(size_t)(k0 + bk) * Nc + col0 + bc];
    }
    __syncthreads();
    #pragma unroll
    for (int kk = 0; kk < 16; kk++) {
      float4 av = *(const float4*)&As[kk][ty * 4];
      float4 bv = *(const float4*)&Bs[kk][tx * 4];
      float a[4] = {av.x, av.y, av.z, av.w};
      float bb[4] = {bv.x, bv.y, bv.z, bv.w};
      #pragma unroll
      for (int i = 0; i < 4; i++)
        #pragma unroll
        for (int j = 0; j < 4; j++)
          acc[i][j] = fmaf(a[i], bb[j], acc[i][j]);
    }
  }
  #pragma unroll
  for (int i = 0; i < 4; i++) {
    int r = row0 + ty * 4 + i;
    if (r < M)
      #pragma unroll
      for (int j = 0; j < 4; j++)
        cs.st(r, col0 + tx * 4 + j, acc[i][j]);
  }
}

// ---------- stage 1: per-(b,f) flash attention, 32 queries/block, chunks of 40 keys ----------
__global__ __launch_bounds__(256) void stage1_attn(const u16* __restrict__ qg,
                                                   const u16* __restrict__ kg,
                                                   const u16* __restrict__ vg,
                                                   u16* __restrict__ xo) {
  __shared__ __align__(16) u16 sq[32][520];
  __shared__ __align__(16) u16 sk[40][520];
  __shared__ __align__(16) u16 sv[40][520];
  __shared__ float ss[32][41];
  __shared__ float red[32][9];
  __shared__ float sm[32], sl[32], srs[32];
  const int tid = threadIdx.x;
  const int qt = blockIdx.x, f = blockIdx.y, b = blockIdx.z;
  const int q0 = qt * 32;
  #pragma unroll
  for (int i = 0; i < 8; i++) {
    int idx = (tid + i * 256) * 8;
    int r = idx >> 9, c = idx & 511;
    uint4 val = make_uint4(0, 0, 0, 0);
    if (q0 + r < NN)
      val = *(const uint4*)&qg[((size_t)b * NN + q0 + r) * CC + c];
    *(uint4*)&sq[r][c] = val;
  }
  if (tid < 32) { sm[tid] = -1e30f; sl[tid] = 0.f; }
  float acc[4][16];
  #pragma unroll
  for (int i = 0; i < 4; i++)
    #pragma unroll
    for (int j = 0; j < 16; j++) acc[i][j] = 0.f;
  const int qb = (tid & 7) * 4;
  const int c0 = (tid >> 3) * 16;
  const size_t kvbase = ((size_t)b * NN + f * PP) * CC;

  for (int ch = 0; ch < 23; ch++) {    // 920 = 23 * 40
    __syncthreads();
    #pragma unroll
    for (int i = 0; i < 10; i++) {
      int idx = (tid + i * 256) * 8;
      int r = idx >> 9, c = idx & 511;
      size_t g = kvbase + (size_t)(ch * 40 + r) * CC + c;
      *(uint4*)&sk[r][c] = *(const uint4*)&kg[g];
      *(uint4*)&sv[r][c] = *(const uint4*)&vg[g];
    }
    __syncthreads();
    #pragma unroll
    for (int pp = 0; pp < 5; pp++) {
      int pr = tid + pp * 256;
      int qi = pr / 40, kj = pr - qi * 40;
      float sum = 0.f;
      for (int c = 0; c < 512; c += 8) {
        uint4 qa = *(const uint4*)&sq[qi][c];
        uint4 ka = *(const uint4*)&sk[kj][c];
        float qf[8], kf[8];
        unpack8(qa, qf); unpack8(ka, kf);
        #pragma unroll
        for (int e = 0; e < 8; e++) sum = fmaf(qf[e], kf[e], sum);
      }
      ss[qi][kj] = sum * 0.125f;
    }
    __syncthreads();
    {
      int qi = tid & 31, part = tid >> 5;
      float mx = ss[qi][part * 5];
      #pragma unroll
      for (int j = 1; j < 5; j++) mx = fmaxf(mx, ss[qi][part * 5 + j]);
      red[qi][part] = mx;
    }
    __syncthreads();
    if (tid < 32) {
      float mx = red[tid][0];
      #pragma unroll
      for (int j = 1; j < 8; j++) mx = fmaxf(mx, red[tid][j]);
      float mold = sm[tid];
      float mnew = fmaxf(mold, mx);
      srs[tid] = __expf(mold - mnew);
      sm[tid] = mnew;
      sl[tid] *= srs[tid];
    }
    __syncthreads();
    {
      int qi = tid & 31, part = tid >> 5;
      float mnew = sm[qi], psum = 0.f;
      #pragma unroll
      for (int j = 0; j < 5; j++) {
        float p = __expf(ss[qi][part * 5 + j] - mnew);
        ss[qi][part * 5 + j] = p;
        psum += p;
      }
      red[qi][part] = psum;
    }
    __syncthreads();
    if (tid < 32) {
      float s = red[tid][0];
      #pragma unroll
      for (int j = 1; j < 8; j++) s += red[tid][j];
      sl[tid] += s;
    }
    {
      float rs0 = srs[qb], rs1 = srs[qb + 1], rs2 = srs[qb + 2], rs3 = srs[qb + 3];
      #pragma unroll
      for (int j = 0; j < 16; j++) {
        acc[0][j] *= rs0; acc[1][j] *= rs1; acc[2][j] *= rs2; acc[3][j] *= rs3;
      }
      for (int kj = 0; kj < 40; kj++) {
        float p0 = ss[qb][kj], p1 = ss[qb + 1][kj], p2 = ss[qb + 2][kj], p3 = ss[qb + 3][kj];
        #pragma unroll
        for (int cc = 0; cc < 16; cc += 8) {
          uint4 va = *(const uint4*)&sv[kj][c0 + cc];
          float vf[8]; unpack8(va, vf);
          #pragma unroll
          for (int e = 0; e < 8; e++) {
            acc[0][cc + e] = fmaf(p0, vf[e], acc[0][cc + e]);
            acc[1][cc + e] = fmaf(p1, vf[e], acc[1][cc + e]);
            acc[2][cc + e] = fmaf(p2, vf[e], acc[2][cc + e]);
            acc[3][cc + e] = fmaf(p3, vf[e], acc[3][cc + e]);
          }
        }
      }
    }
  }
  __syncthreads();
  #pragma unroll
  for (int i = 0; i < 4; i++) {
    int qgbl = q0 + qb + i;
    if (qgbl < NN) {
      float inv = 1.f / sl[qb + i];
      uint4 o0, o1;
      o0.x = pack2(acc[i][0] * inv,  acc[i][1] * inv);
      o0.y = pack2(acc[i][2] * inv,  acc[i][3] * inv);
      o0.z = pack2(acc[i][4] * inv,  acc[i][5] * inv);
      o0.w = pack2(acc[i][6] * inv,  acc[i][7] * inv);
      o1.x = pack2(acc[i][8] * inv,  acc[i][9] * inv);
      o1.y = pack2(acc[i][10] * inv, acc[i][11] * inv);
      o1.z = pack2(acc[i][12] * inv, acc[i][13] * inv);
      o1.w = pack2(acc[i][14] * inv, acc[i][15] * inv);
      size_t base = (((size_t)b * NN + qgbl) * FF + f) * CC + c0;
      *(uint4*)&xo[base]     = o0;
      *(uint4*)&xo[base + 8] = o1;
    }
  }
}

// ---------- fused k2-GEMM + q2 dot -> raw logits (attn2 layout (B,h,N,F)) ----------
// One col-tile (64 cols) == one head. Block fully owns head dim -> no atomics.
__global__ __launch_bounds__(256) void gemm_logits(const u16* __restrict__ xo,
                                                   const u16* __restrict__ q2,
                                                   const float* __restrict__ Wkv2,
                                                   float* __restrict__ attn2) {
  __shared__ __align__(16) float As[16][68];
  __shared__ __align__(16) float Bs[16][68];
  __shared__ float rr[64][17];
  const int tid = threadIdx.x;
  const int tx = tid & 15, ty = tid >> 4;
  const int row0 = blockIdx.y * 64;      // rows r2 = ((b*4600+s)*5+f)
  const int h = blockIdx.x;              // head
  const int col0 = h * 64;
  float acc[4][4] = {};
  for (int k0 = 0; k0 < 512; k0 += 16) {
    __syncthreads();
    #pragma unroll
    for (int i = 0; i < 4; i++) {
      int idx = tid + i * 256;
      int ak = idx & 15, ar = idx >> 4;
      int r = row0 + ar;
      As[ak][ar] = (r < 92000) ? bf2f(xo[(size_t)r * CC + k0 + ak]) : 0.f;
    }
    #pragma unroll
    for (int i = 0; i < 4; i++) {
      int idx = tid + i * 256;
      int bk = idx >> 6, bc = idx & 63;
      Bs[bk][bc] = Wkv2[(size_t)(k0 + bk) * 1024 + col0 + bc];   // W_k2 cols
    }
    __syncthreads();
    #pragma unroll
    for (int kk = 0; kk < 16; kk++) {
      float4 av = *(const float4*)&As[kk][ty * 4];
      float4 bv = *(const float4*)&Bs[kk][tx * 4];
      float a[4] = {av.x, av.y, av.z, av.w};
      float bb[4] = {bv.x, bv.y, bv.z, bv.w};
      #pragma unroll
      for (int i = 0; i < 4; i++)
        #pragma unroll
        for (int j = 0; j < 4; j++)
          acc[i][j] = fmaf(a[i], bb[j], acc[i][j]);
    }
  }
  // epilogue: logit partial = sum_j k2[r, h*64 + tx*4+j] * q2[(b,s), h*64 + tx*4+j]
  #pragma unroll
  for (int i = 0; i < 4; i++) {
    int r = row0 + ty * 4 + i;
    float p = 0.f;
    if (r < 92000) {
      int q2row = r / 5;                 // (b*4600+s)
      #pragma unroll
      for (int j = 0; j < 4; j++)
        p += acc[i][j] * bf2f(q2[(size_t)q2row * CC + col0 + tx * 4 + j]);
    }
    rr[ty * 4 + i][tx] = p;
  }
  __syncthreads();
  if (tid < 64) {
    int r = row0 + tid;
    if (r < 92000) {
      float s = 0.f;
      #pragma unroll
      for (int j = 0; j < 16; j++) s += rr[tid][j];
      int b = r / (NN * FF), rem = r - b * (NN * FF);
      int sIdx = rem / FF, f = rem - sIdx * FF;
      attn2[(((size_t)b * 8 + h) * NN + sIdx) * FF + f] = s;
    }
  }
}

// ---------- softmax over F=5, in place on attn2 ----------
__global__ __launch_bounds__(256) void softmax_f5(float* __restrict__ a) {
  int t = blockIdx.x * 256 + threadIdx.x;
  if (t >= NB * 8 * NN) return;
  float* p = a + (size_t)t * FF;
  float l0 = p[0], l1 = p[1], l2 = p[2], l3 = p[3], l4 = p[4];
  float m = fmaxf(fmaxf(fmaxf(l0, l1), fmaxf(l2, l3)), l4);
  float e0 = __expf(l0 - m), e1 = __expf(l1 - m), e2 = __expf(l2 - m),
        e3 = __expf(l3 - m), e4 = __expf(l4 - m);
  float inv = 1.f / (e0 + e1 + e2 + e3 + e4);
  p[0] = e0 * inv; p[1] = e1 * inv; p[2] = e2 * inv; p[3] = e3 * inv; p[4] = e4 * inv;
}

// ---------- fused attn-weighted mix + W_v2 GEMM -> out_pre (bf16) ----------
// out_pre[(b,s), h*64+d] = (sum_f attn2[b,h,s,f] * xo[b,s,f,:]) @ W_v2[:, h*64+d]
__global__ __launch_bounds__(256) void gemm_mix(const u16* __restrict__ xo,
                                                const float* __restrict__ attn2,
                                                const float* __restrict__ Wkv2,
                                                u16* __restrict__ outp) {
  __shared__ __align__(16) float As[16][68];
  __shared__ __align__(16) float Bs[16][68];
  __shared__ float aw[64][5];
  const int tid = threadIdx.x;
  const int tx = tid & 15, ty = tid >> 4;
  const int row0 = blockIdx.y * 64;      // rows (b*4600+s)
  const int h = blockIdx.x;
  const int col0 = h * 64;
  if (tid < 64) {
    int r = row0 + tid;
    if (r < 18400) {
      int b = r / NN, s = r - b * NN;
      size_t base = (((size_t)b * 8 + h) * NN + s) * FF;
      #pragma unroll
      for (int f = 0; f < FF; f++) aw[tid][f] = attn2[base + f];
    } else {
      #pragma unroll
      for (int f = 0; f < FF; f++) aw[tid][f] = 0.f;
    }
  }
  float acc[4][4] = {};
  for (int k0 = 0; k0 < 512; k0 += 16) {
    __syncthreads();
    #pragma unroll
    for (int i = 0; i < 4; i++) {
      int idx = tid + i * 256;
      int ak = idx & 15, ar = idx >> 4;
      int r = row0 + ar;
      float aval = 0.f;
      if (r < 18400) {
        size_t xb = ((size_t)r * FF) * CC + k0 + ak;
        #pragma unroll
        for (int f = 0; f < FF; f++)
          aval = fmaf(aw[ar][f], bf2f(xo[xb + (size_t)f * CC]), aval);
      }
      As[ak][ar] = aval;
    }
    #pragma unroll
    for (int i = 0; i < 4; i++) {
      int idx = tid + i * 256;
      int bk = idx >> 6, bc = idx & 63;
      Bs[bk][bc] = Wkv2[(size_t)(k0 + bk) * 1024 + 512 + col0 + bc];  // W_v2 cols
    }
    __syncthreads();
    #pragma unroll
    for (int kk = 0; kk < 16; kk++) {
      float4 av = *(const float4*)&As[kk][ty * 4];
      float4 bv = *(const float4*)&Bs[kk][tx * 4];
      float a[4] = {av.x, av.y, av.z, av.w};
      float bb[4] = {bv.x, bv.y, bv.z, bv.w};
      #pragma unroll
      for (int i = 0; i < 4; i++)
        #pragma unroll
        for (int j = 0; j < 4; j++)
          acc[i][j] = fmaf(a[i], bb[j], acc[i][j]);
    }
  }
  #pragma unroll
  for (int i = 0; i < 4; i++) {
    int r = row0 + ty * 4 + i;
    if (r < 18400)
      #pragma unroll
      for (int j = 0; j < 4; j++)
        outp[(size_t)r * CC + col0 + tx * 4 + j] = f2bf(acc[i][j]);
  }
}

// ---------- sentinel: distinguishes "ws too small" in bench output ----------
__global__ void sentinel_fill(float* o) { o[threadIdx.x] = 777.0f; }

// ---------- launcher ----------
extern "C" void kernel_launch(void* const* d_in, const int* in_sizes, int n_in,
                              void* d_out, int out_size, void* d_ws, size_t ws_size,
                              hipStream_t stream) {
  const float* x     = (const float*)d_in[0];
  const float* Wqkv  = (const float*)d_in[1];
  const float* Wq2   = (const float*)d_in[2];
  const float* Wkv2  = (const float*)d_in[3];
  const float* Wproj = (const float*)d_in[4];
  const float* bproj = (const float*)d_in[5];
  float* out   = (float*)d_out;
  float* attn2 = out + (size_t)PP * NB * FF * CC;   // +9,420,800 elements

  // workspace layout (bf16), with aliasing:
  //   [0, SZ)        q      -> later q2
  //   [SZ, 2SZ)      k      -> later out_pre
  //   [2SZ, 3SZ)     v
  //   [3SZ, 3SZ+XO)  xo
  char* ws = (char*)d_ws;
  const size_t SZ = (size_t)18400 * CC * 2;          // 18,841,600 B
  const size_t XO = (size_t)92000 * CC * 2;          // 94,208,000 B
  const size_t NEED = 3 * SZ + XO;                   // 150,732,800 B
  if (ws_size < NEED) {                              // diagnostic signature
    sentinel_fill<<<1, 256, 0, stream>>>(out);
    return;
  }
  u16* q    = (u16*)(ws);
  u16* k    = (u16*)(ws + SZ);
  u16* v    = (u16*)(ws + 2 * SZ);
  u16* xo   = (u16*)(ws + 3 * SZ);
  u16* q2   = (u16*)(ws);            // alias q (dead after stage1)
  u16* outp = (u16*)(ws + SZ);       // alias k (dead after stage1)

  // 1) QKV projection
  {
    AProvX ap{x}; CSinkQKV cs{q, k, v};
    gemm64<<<dim3(24, 288), 256, 0, stream>>>(ap, Wqkv, cs, 18400, 512, 1536);
  }
  // 2) stage-1 space attention -> xo (B,N,F,C)
  stage1_attn<<<dim3(144, 5, 4), 256, 0, stream>>>(q, k, v, xo);
  // 3) q2 = diag(xo) @ W_q2 * scale   (overwrites q region)
  {
    AProvDiag ap{xo}; CSinkQ2 cs{q2};
    gemm64<<<dim3(8, 288), 256, 0, stream>>>(ap, Wq2, cs, 18400, 512, 512);
  }
  // 4) fused k2-GEMM + q2 dot -> raw logits into attn2 slice of d_out
  gemm_logits<<<dim3(8, 1438), 256, 0, stream>>>(xo, q2, Wkv2, attn2);
  // 5) softmax over F in place
  softmax_f5<<<(NB * 8 * NN + 255) / 256, 256, 0, stream>>>(attn2);
  // 6) fused mix + W_v2 -> out_pre (overwrites k region)
  gemm_mix<<<dim3(8, 288), 256, 0, stream>>>(xo, attn2, Wkv2, outp);
  // 7) final projection + bias + permute to (P, B*F, C)
  {
    AProvBF ap{outp}; CSinkProj cs{out, bproj};
    gemm64<<<dim3(8, 288), 256, 0, stream>>>(ap, Wproj, cs, 18400, 512, 512);
  }
}

// Round 3
// 2878.057 us; speedup vs baseline: 3.3729x; 3.3729x over previous
//
#include <hip/hip_runtime.h>
#include <hip/hip_bf16.h>
#include <stdint.h>

typedef unsigned short u16;
typedef unsigned int   u32;
typedef __attribute__((ext_vector_type(8))) short short8;
typedef __attribute__((ext_vector_type(4))) float f32x4;

// ---------- bf16 helpers (storage-only bf16, f32 math) ----------
__device__ __forceinline__ float bf2f(u16 a) {
  union { u32 i; float f; } t; t.i = ((u32)a) << 16; return t.f;
}
__device__ __forceinline__ u16 f2bf(float f) {
  union { u32 i; float f; } t; t.f = f;
  u32 r = t.i + 0x7fffu + ((t.i >> 16) & 1u);   // round-nearest-even
  return (u16)(r >> 16);
}
__device__ __forceinline__ u32 pack2(float a, float b) {
  return (u32)f2bf(a) | ((u32)f2bf(b) << 16);
}

#define NB 4
#define NN 4600
#define FF 5
#define PP 920
#define CC 512

// ---------- generic 64x64 f32 tiled GEMM (A via provider, C via sink) ----------
struct AProvX {        // A row r=(b,n) -> x[n,b,c]   (f32 input)
  const float* x;
  __device__ __forceinline__ float ld(int r, int k) const {
    int b = r / NN, n = r - b * NN;
    return x[((size_t)n * NB + b) * CC + k];
  }
};
struct AProvBF {       // contiguous bf16 rows, stride 512
  const u16* a;
  __device__ __forceinline__ float ld(int r, int k) const {
    return bf2f(a[(size_t)r * CC + k]);
  }
};
struct AProvDiag {     // x_diag: row (b,n) -> xo[b,n, n/P, c]
  const u16* xo;
  __device__ __forceinline__ float ld(int r, int k) const {
    int b = r / NN, n = r - b * NN;
    int f = n / PP;
    return bf2f(xo[(((size_t)b * NN + n) * FF + f) * CC + k]);
  }
};
struct CSinkQKV {      // split 1536 cols: q,k row-major; v stored TRANSPOSED per (b,f): vt[b][f][c][p]
  u16 *q, *k, *vt;
  __device__ __forceinline__ void st(int r, int c, float val) const {
    u16 hv = f2bf(val);
    if (c < 512)        q[(size_t)r * CC + c] = hv;
    else if (c < 1024)  k[(size_t)r * CC + (c - 512)] = hv;
    else {
      int b = r / NN, n = r - b * NN;
      int f = n / PP, p = n - f * PP;
      vt[(((size_t)(b * FF + f)) * CC + (c - 1024)) * PP + p] = hv;
    }
  }
};
struct CSinkQ2 {       // bf16 * scale (dh^-0.5 = 0.125)
  u16* o;
  __device__ __forceinline__ void st(int r, int c, float v) const {
    o[(size_t)r * CC + c] = f2bf(v * 0.125f);
  }
};
struct CSinkProj {     // + bias, scatter to (P, B*F, C) f32
  float* out; const float* bias;
  __device__ __forceinline__ void st(int r, int c, float v) const {
    int b = r / NN, rem = r - b * NN;
    int f = rem / PP, p = rem - f * PP;
    out[((size_t)p * (NB * FF) + b * FF + f) * CC + c] = v + bias[c];
  }
};

template<class AP, class CS>
__global__ __launch_bounds__(256) void gemm64(AP ap, const float* __restrict__ Bm,
                                              CS cs, int M, int K, int Nc) {
  __shared__ __align__(16) float As[16][68];
  __shared__ __align__(16) float Bs[16][68];
  const int tid = threadIdx.x;
  const int tx = tid & 15, ty = tid >> 4;
  const int row0 = blockIdx.y * 64, col0 = blockIdx.x * 64;
  float acc[4][4] = {};
  for (int k0 = 0; k0 < K; k0 += 16) {
    __syncthreads();
    #pragma unroll
    for (int i = 0; i < 4; i++) {
      int idx = tid + i * 256;
      int ak = idx & 15, ar = idx >> 4;
      int r = row0 + ar;
      As[ak][ar] = (r < M) ? ap.ld(r, k0 + ak) : 0.f;
    }
    #pragma unroll
    for (int i = 0; i < 4; i++) {
      int idx = tid + i * 256;
      int bk = idx >> 6, bc = idx & 63;
      Bs[bk][bc] = Bm[(size_t)(k0 + bk) * Nc + col0 + bc];
    }
    __syncthreads();
    #pragma unroll
    for (int kk = 0; kk < 16; kk++) {
      float4 av = *(const float4*)&As[kk][ty * 4];
      float4 bv = *(const float4*)&Bs[kk][tx * 4];
      float a[4] = {av.x, av.y, av.z, av.w};
      float bb[4] = {bv.x, bv.y, bv.z, bv.w};
      #pragma unroll
      for (int i = 0; i < 4; i++)
        #pragma unroll
        for (int j = 0; j < 4; j++)
          acc[i][j] = fmaf(a[i], bb[j], acc[i][j]);
    }
  }
  #pragma unroll
  for (int i = 0; i < 4; i++) {
    int r = row0 + ty * 4 + i;
    if (r < M)
      #pragma unroll
      for (int j = 0; j < 4; j++)
        cs.st(r, col0 + tx * 4 + j, acc[i][j]);
  }
}

// ---------- stage 1 (MFMA): per-(b,f) flash attention, 32 q/block, 32-key chunks ----------
// Wave w=(qh,kh) computes S quadrant via MFMA; all waves cooperate on softmax;
// wave w owns output channels [w*128, w*128+128) for PV. Q frags persistent in VGPR.
// K frags: 16B/lane direct global loads (row-major K). V frags: 16B/lane from vt (transposed V).
__global__ __launch_bounds__(256, 2) void stage1_mfma(const u16* __restrict__ qg,
                                                      const u16* __restrict__ kg,
                                                      const u16* __restrict__ vt,
                                                      u16* __restrict__ xo) {
  __shared__ float S[32][33];
  __shared__ __align__(16) u16 Pb[32][40];
  __shared__ float red[32][9];
  __shared__ float sm[32], sl[32], srs[32];
  const int tid = threadIdx.x;
  const int qt = blockIdx.x, f = blockIdx.y, b = blockIdx.z;
  const int q0 = qt * 32;
  const int wid = tid >> 6, lane = tid & 63;
  const int lr = lane & 15, lg = lane >> 4;
  const int qh = wid >> 1, kh = wid & 1;
  const int c0w = wid * 128;

  // persistent Q fragments: Q[q0+qh*16+lr][ck*32 + lg*8 .. +7]
  short8 qf[16];
  {
    int qrow = q0 + qh * 16 + lr; if (qrow > NN - 1) qrow = NN - 1;
    const u16* qb = qg + ((size_t)b * NN + qrow) * CC + lg * 8;
    #pragma unroll
    for (int ck = 0; ck < 16; ck++)
      qf[ck] = *(const short8*)(qb + ck * 32);
  }
  if (tid < 32) { sm[tid] = -1e30f; sl[tid] = 0.f; }
  f32x4 acc[2][8];
  #pragma unroll
  for (int i = 0; i < 2; i++)
    #pragma unroll
    for (int j = 0; j < 8; j++) acc[i][j] = (f32x4){0.f, 0.f, 0.f, 0.f};

  const size_t kgbase = (size_t)b * NN + f * PP;
  const u16* vtb = vt + (((size_t)(b * FF + f)) * CC + c0w + lr) * PP;

  for (int ch = 0; ch < 29; ch++) {         // 920 = 28*32 + 24
    const int kk0 = ch * 32;
    const int nv = (ch == 28) ? 24 : 32;
    // ---- QK^T quadrant (16 MFMAs over 512 channels) ----
    {
      int key = kk0 + kh * 16 + lr; if (key > PP - 1) key = PP - 1;
      const u16* kb = kg + (kgbase + key) * CC + lg * 8;
      f32x4 sacc = (f32x4){0.f, 0.f, 0.f, 0.f};
      #pragma unroll
      for (int ck = 0; ck < 16; ck++) {
        short8 kf = *(const short8*)(kb + ck * 32);
        sacc = __builtin_amdgcn_mfma_f32_16x16x32_bf16(qf[ck], kf, sacc, 0, 0, 0);
      }
      #pragma unroll
      for (int r = 0; r < 4; r++)
        S[qh * 16 + lg * 4 + r][kh * 16 + lr] = sacc[r] * 0.125f;
    }
    __syncthreads();                        // A: S complete
    {                                       // partial max (4 cols/thread)
      int srow = tid & 31, part = tid >> 5;
      float mx = -1e30f;
      #pragma unroll
      for (int j = 0; j < 4; j++) {
        int col = part * 4 + j;
        float sv = (col < nv) ? S[srow][col] : -1e30f;
        mx = fmaxf(mx, sv);
      }
      red[srow][part] = mx;
    }
    __syncthreads();                        // B
    if (tid < 32) {
      float mx = red[tid][0];
      #pragma unroll
      for (int j = 1; j < 8; j++) mx = fmaxf(mx, red[tid][j]);
      float mold = sm[tid];
      float mnew = fmaxf(mold, mx);
      srs[tid] = __expf(mold - mnew);
      sm[tid] = mnew;
      sl[tid] *= srs[tid];
    }
    __syncthreads();                        // C: sm/srs ready
    {                                       // exp + P(bf16) + partial sum
      int srow = tid & 31, part = tid >> 5;
      float mnew = sm[srow], psum = 0.f;
      #pragma unroll
      for (int j = 0; j < 4; j++) {
        int col = part * 4 + j;
        float p = (col < nv) ? __expf(S[srow][col] - mnew) : 0.f;
        Pb[srow][col] = f2bf(p);
        psum += p;
      }
      red[srow][part] = psum;
    }
    __syncthreads();                        // D: P ready
    if (tid < 32) {
      float s2 = 0.f;
      #pragma unroll
      for (int j = 0; j < 8; j++) s2 += red[tid][j];
      sl[tid] += s2;
    }
    // ---- rescale + PV (16 MFMAs: 2 q-halves x 8 col-tiles) ----
    {
      float rs[2][4];
      #pragma unroll
      for (int i = 0; i < 2; i++)
        #pragma unroll
        for (int r = 0; r < 4; r++) rs[i][r] = srs[i * 16 + lg * 4 + r];
      #pragma unroll
      for (int i = 0; i < 2; i++)
        #pragma unroll
        for (int j = 0; j < 8; j++)
          #pragma unroll
          for (int r = 0; r < 4; r++) acc[i][j][r] *= rs[i][r];
      short8 pf[2];
      #pragma unroll
      for (int i = 0; i < 2; i++)
        pf[i] = *(const short8*)&Pb[i * 16 + lr][lg * 8];
      int kidx = kk0 + lg * 8; if (kidx > PP - 8) kidx = PP - 8;
      const u16* vb = vtb + kidx;
      #pragma unroll
      for (int ct = 0; ct < 8; ct++) {
        short8 vf = *(const short8*)(vb + (size_t)ct * 16 * PP);
        acc[0][ct] = __builtin_amdgcn_mfma_f32_16x16x32_bf16(pf[0], vf, acc[0][ct], 0, 0, 0);
        acc[1][ct] = __builtin_amdgcn_mfma_f32_16x16x32_bf16(pf[1], vf, acc[1][ct], 0, 0, 0);
      }
    }
  }
  __syncthreads();                          // E: sl final
  {
    float inv[2][4];
    #pragma unroll
    for (int i = 0; i < 2; i++)
      #pragma unroll
      for (int r = 0; r < 4; r++) inv[i][r] = 1.f / sl[i * 16 + lg * 4 + r];
    #pragma unroll
    for (int i = 0; i < 2; i++) {
      #pragma unroll
      for (int r = 0; r < 4; r++) {
        int q = q0 + i * 16 + lg * 4 + r;
        if (q < NN) {
          size_t base = ((size_t)(b * NN + q) * FF + f) * CC + c0w + lr;
          #pragma unroll
          for (int ct = 0; ct < 8; ct++)
            xo[base + ct * 16] = f2bf(acc[i][ct][r] * inv[i][r]);
        }
      }
    }
  }
}

// ---------- fused k2-GEMM + q2 dot -> raw logits (attn2 layout (B,h,N,F)) ----------
__global__ __launch_bounds__(256) void gemm_logits(const u16* __restrict__ xo,
                                                   const u16* __restrict__ q2,
                                                   const float* __restrict__ Wkv2,
                                                   float* __restrict__ attn2) {
  __shared__ __align__(16) float As[16][68];
  __shared__ __align__(16) float Bs[16][68];
  __shared__ float rr[64][17];
  const int tid = threadIdx.x;
  const int tx = tid & 15, ty = tid >> 4;
  const int row0 = blockIdx.y * 64;
  const int h = blockIdx.x;
  const int col0 = h * 64;
  float acc[4][4] = {};
  for (int k0 = 0; k0 < 512; k0 += 16) {
    __syncthreads();
    #pragma unroll
    for (int i = 0; i < 4; i++) {
      int idx = tid + i * 256;
      int ak = idx & 15, ar = idx >> 4;
      int r = row0 + ar;
      As[ak][ar] = (r < 92000) ? bf2f(xo[(size_t)r * CC + k0 + ak]) : 0.f;
    }
    #pragma unroll
    for (int i = 0; i < 4; i++) {
      int idx = tid + i * 256;
      int bk = idx >> 6, bc = idx & 63;
      Bs[bk][bc] = Wkv2[(size_t)(k0 + bk) * 1024 + col0 + bc];
    }
    __syncthreads();
    #pragma unroll
    for (int kk = 0; kk < 16; kk++) {
      float4 av = *(const float4*)&As[kk][ty * 4];
      float4 bv = *(const float4*)&Bs[kk][tx * 4];
      float a[4] = {av.x, av.y, av.z, av.w};
      float bb[4] = {bv.x, bv.y, bv.z, bv.w};
      #pragma unroll
      for (int i = 0; i < 4; i++)
        #pragma unroll
        for (int j = 0; j < 4; j++)
          acc[i][j] = fmaf(a[i], bb[j], acc[i][j]);
    }
  }
  #pragma unroll
  for (int i = 0; i < 4; i++) {
    int r = row0 + ty * 4 + i;
    float p = 0.f;
    if (r < 92000) {
      int q2row = r / 5;
      #pragma unroll
      for (int j = 0; j < 4; j++)
        p += acc[i][j] * bf2f(q2[(size_t)q2row * CC + col0 + tx * 4 + j]);
    }
    rr[ty * 4 + i][tx] = p;
  }
  __syncthreads();
  if (tid < 64) {
    int r = row0 + tid;
    if (r < 92000) {
      float s = 0.f;
      #pragma unroll
      for (int j = 0; j < 16; j++) s += rr[tid][j];
      int b = r / (NN * FF), rem = r - b * (NN * FF);
      int sIdx = rem / FF, f = rem - sIdx * FF;
      attn2[(((size_t)b * 8 + h) * NN + sIdx) * FF + f] = s;
    }
  }
}

// ---------- softmax over F=5, in place on attn2 ----------
__global__ __launch_bounds__(256) void softmax_f5(float* __restrict__ a) {
  int t = blockIdx.x * 256 + threadIdx.x;
  if (t >= NB * 8 * NN) return;
  float* p = a + (size_t)t * FF;
  float l0 = p[0], l1 = p[1], l2 = p[2], l3 = p[3], l4 = p[4];
  float m = fmaxf(fmaxf(fmaxf(l0, l1), fmaxf(l2, l3)), l4);
  float e0 = __expf(l0 - m), e1 = __expf(l1 - m), e2 = __expf(l2 - m),
        e3 = __expf(l3 - m), e4 = __expf(l4 - m);
  float inv = 1.f / (e0 + e1 + e2 + e3 + e4);
  p[0] = e0 * inv; p[1] = e1 * inv; p[2] = e2 * inv; p[3] = e3 * inv; p[4] = e4 * inv;
}

// ---------- fused attn-weighted mix + W_v2 GEMM -> out_pre (bf16) ----------
__global__ __launch_bounds__(256) void gemm_mix(const u16* __restrict__ xo,
                                                const float* __restrict__ attn2,
                                                const float* __restrict__ Wkv2,
                                                u16* __restrict__ outp) {
  __shared__ __align__(16) float As[16][68];
  __shared__ __align__(16) float Bs[16][68];
  __shared__ float aw[64][5];
  const int tid = threadIdx.x;
  const int tx = tid & 15, ty = tid >> 4;
  const int row0 = blockIdx.y * 64;
  const int h = blockIdx.x;
  const int col0 = h * 64;
  if (tid < 64) {
    int r = row0 + tid;
    if (r < 18400) {
      int b = r / NN, s = r - b * NN;
      size_t base = (((size_t)b * 8 + h) * NN + s) * FF;
      #pragma unroll
      for (int f = 0; f < FF; f++) aw[tid][f] = attn2[base + f];
    } else {
      #pragma unroll
      for (int f = 0; f < FF; f++) aw[tid][f] = 0.f;
    }
  }
  float acc[4][4] = {};
  for (int k0 = 0; k0 < 512; k0 += 16) {
    __syncthreads();
    #pragma unroll
    for (int i = 0; i < 4; i++) {
      int idx = tid + i * 256;
      int ak = idx & 15, ar = idx >> 4;
      int r = row0 + ar;
      float aval = 0.f;
      if (r < 18400) {
        size_t xb = ((size_t)r * FF) * CC + k0 + ak;
        #pragma unroll
        for (int f = 0; f < FF; f++)
          aval = fmaf(aw[ar][f], bf2f(xo[xb + (size_t)f * CC]), aval);
      }
      As[ak][ar] = aval;
    }
    #pragma unroll
    for (int i = 0; i < 4; i++) {
      int idx = tid + i * 256;
      int bk = idx >> 6, bc = idx & 63;
      Bs[bk][bc] = Wkv2[(size_t)(k0 + bk) * 1024 + 512 + col0 + bc];
    }
    __syncthreads();
    #pragma unroll
    for (int kk = 0; kk < 16; kk++) {
      float4 av = *(const float4*)&As[kk][ty * 4];
      float4 bv = *(const float4*)&Bs[kk][tx * 4];
      float a[4] = {av.x, av.y, av.z, av.w};
      float bb[4] = {bv.x, bv.y, bv.z, bv.w};
      #pragma unroll
      for (int i = 0; i < 4; i++)
        #pragma unroll
        for (int j = 0; j < 4; j++)
          acc[i][j] = fmaf(a[i], bb[j], acc[i][j]);
    }
  }
  #pragma unroll
  for (int i = 0; i < 4; i++) {
    int r = row0 + ty * 4 + i;
    if (r < 18400)
      #pragma unroll
      for (int j = 0; j < 4; j++)
        outp[(size_t)r * CC + col0 + tx * 4 + j] = f2bf(acc[i][j]);
  }
}

// ---------- sentinel: distinguishes "ws too small" in bench output ----------
__global__ void sentinel_fill(float* o) { o[threadIdx.x] = 777.0f; }

// ---------- launcher ----------
extern "C" void kernel_launch(void* const* d_in, const int* in_sizes, int n_in,
                              void* d_out, int out_size, void* d_ws, size_t ws_size,
                              hipStream_t stream) {
  const float* x     = (const float*)d_in[0];
  const float* Wqkv  = (const float*)d_in[1];
  const float* Wq2   = (const float*)d_in[2];
  const float* Wkv2  = (const float*)d_in[3];
  const float* Wproj = (const float*)d_in[4];
  const float* bproj = (const float*)d_in[5];
  float* out   = (float*)d_out;
  float* attn2 = out + (size_t)PP * NB * FF * CC;

  char* ws = (char*)d_ws;
  const size_t SZ = (size_t)18400 * CC * 2;
  const size_t XO = (size_t)92000 * CC * 2;
  const size_t NEED = 3 * SZ + XO;            // 150,732,800 B
  if (ws_size < NEED) {
    sentinel_fill<<<1, 256, 0, stream>>>(out);
    return;
  }
  u16* q    = (u16*)(ws);
  u16* k    = (u16*)(ws + SZ);
  u16* vt   = (u16*)(ws + 2 * SZ);
  u16* xo   = (u16*)(ws + 3 * SZ);
  u16* q2   = (u16*)(ws);            // alias q (dead after stage1)
  u16* outp = (u16*)(ws + SZ);       // alias k (dead after stage1)

  // 1) QKV projection (v written transposed per (b,f))
  {
    AProvX ap{x}; CSinkQKV cs{q, k, vt};
    gemm64<<<dim3(24, 288), 256, 0, stream>>>(ap, Wqkv, cs, 18400, 512, 1536);
  }
  // 2) stage-1 space attention (MFMA) -> xo (B,N,F,C)
  stage1_mfma<<<dim3(144, 5, 4), 256, 0, stream>>>(q, k, vt, xo);
  // 3) q2 = diag(xo) @ W_q2 * scale   (overwrites q region)
  {
    AProvDiag ap{xo}; CSinkQ2 cs{q2};
    gemm64<<<dim3(8, 288), 256, 0, stream>>>(ap, Wq2, cs, 18400, 512, 512);
  }
  // 4) fused k2-GEMM + q2 dot -> raw logits into attn2 slice of d_out
  gemm_logits<<<dim3(8, 1438), 256, 0, stream>>>(xo, q2, Wkv2, attn2);
  // 5) softmax over F in place
  softmax_f5<<<(NB * 8 * NN + 255) / 256, 256, 0, stream>>>(attn2);
  // 6) fused mix + W_v2 -> out_pre (overwrites k region)
  gemm_mix<<<dim3(8, 288), 256, 0, stream>>>(xo, attn2, Wkv2, outp);
  // 7) final projection + bias + permute to (P, B*F, C)
  {
    AProvBF ap{outp}; CSinkProj cs{out, bproj};
    gemm64<<<dim3(8, 288), 256, 0, stream>>>(ap, Wproj, cs, 18400, 512, 512);
  }
}

// Round 4
// 2623.310 us; speedup vs baseline: 3.7004x; 1.0971x over previous
//
#include <hip/hip_runtime.h>
#include <hip/hip_bf16.h>
#include <stdint.h>

typedef unsigned short u16;
typedef unsigned int   u32;
typedef __attribute__((ext_vector_type(8))) short short8;
typedef __attribute__((ext_vector_type(4))) float f32x4;

// ---------- bf16 helpers (storage-only bf16, f32 math) ----------
__device__ __forceinline__ float bf2f(u16 a) {
  union { u32 i; float f; } t; t.i = ((u32)a) << 16; return t.f;
}
__device__ __forceinline__ u16 f2bf(float f) {
  union { u32 i; float f; } t; t.f = f;
  u32 r = t.i + 0x7fffu + ((t.i >> 16) & 1u);   // round-nearest-even
  return (u16)(r >> 16);
}
__device__ __forceinline__ u32 pack2(float a, float b) {
  return (u32)f2bf(a) | ((u32)f2bf(b) << 16);
}

#define NB 4
#define NN 4600
#define FF 5
#define PP 920
#define CC 512

// ---------- generic 64x64 f32 tiled GEMM (A via provider, C via sink) ----------
struct AProvX {        // A row r=(b,n) -> x[n,b,c]   (f32 input)
  const float* x;
  __device__ __forceinline__ float ld(int r, int k) const {
    int b = r / NN, n = r - b * NN;
    return x[((size_t)n * NB + b) * CC + k];
  }
};
struct AProvBF {       // contiguous bf16 rows, stride 512
  const u16* a;
  __device__ __forceinline__ float ld(int r, int k) const {
    return bf2f(a[(size_t)r * CC + k]);
  }
};
struct AProvDiag {     // x_diag: row (b,n) -> xo[b,n, n/P, c]
  const u16* xo;
  __device__ __forceinline__ float ld(int r, int k) const {
    int b = r / NN, n = r - b * NN;
    int f = n / PP;
    return bf2f(xo[(((size_t)b * NN + n) * FF + f) * CC + k]);
  }
};
struct CSinkQKV {      // split 1536 cols: q,k row-major; v stored TRANSPOSED per (b,f): vt[b][f][c][p]
  u16 *q, *k, *vt;
  __device__ __forceinline__ void st(int r, int c, float val) const {
    u16 hv = f2bf(val);
    if (c < 512)        q[(size_t)r * CC + c] = hv;
    else if (c < 1024)  k[(size_t)r * CC + (c - 512)] = hv;
    else {
      int b = r / NN, n = r - b * NN;
      int f = n / PP, p = n - f * PP;
      vt[(((size_t)(b * FF + f)) * CC + (c - 1024)) * PP + p] = hv;
    }
  }
};
struct CSinkQ2 {       // bf16 * scale (dh^-0.5 = 0.125)
  u16* o;
  __device__ __forceinline__ void st(int r, int c, float v) const {
    o[(size_t)r * CC + c] = f2bf(v * 0.125f);
  }
};
struct CSinkProj {     // + bias, scatter to (P, B*F, C) f32
  float* out; const float* bias;
  __device__ __forceinline__ void st(int r, int c, float v) const {
    int b = r / NN, rem = r - b * NN;
    int f = rem / PP, p = rem - f * PP;
    out[((size_t)p * (NB * FF) + b * FF + f) * CC + c] = v + bias[c];
  }
};

template<class AP, class CS>
__global__ __launch_bounds__(256) void gemm64(AP ap, const float* __restrict__ Bm,
                                              CS cs, int M, int K, int Nc) {
  __shared__ __align__(16) float As[16][68];
  __shared__ __align__(16) float Bs[16][68];
  const int tid = threadIdx.x;
  const int tx = tid & 15, ty = tid >> 4;
  const int row0 = blockIdx.y * 64, col0 = blockIdx.x * 64;
  float acc[4][4] = {};
  for (int k0 = 0; k0 < K; k0 += 16) {
    __syncthreads();
    #pragma unroll
    for (int i = 0; i < 4; i++) {
      int idx = tid + i * 256;
      int ak = idx & 15, ar = idx >> 4;
      int r = row0 + ar;
      As[ak][ar] = (r < M) ? ap.ld(r, k0 + ak) : 0.f;
    }
    #pragma unroll
    for (int i = 0; i < 4; i++) {
      int idx = tid + i * 256;
      int bk = idx >> 6, bc = idx & 63;
      Bs[bk][bc] = Bm[(size_t)(k0 + bk) * Nc + col0 + bc];
    }
    __syncthreads();
    #pragma unroll
    for (int kk = 0; kk < 16; kk++) {
      float4 av = *(const float4*)&As[kk][ty * 4];
      float4 bv = *(const float4*)&Bs[kk][tx * 4];
      float a[4] = {av.x, av.y, av.z, av.w};
      float bb[4] = {bv.x, bv.y, bv.z, bv.w};
      #pragma unroll
      for (int i = 0; i < 4; i++)
        #pragma unroll
        for (int j = 0; j < 4; j++)
          acc[i][j] = fmaf(a[i], bb[j], acc[i][j]);
    }
  }
  #pragma unroll
  for (int i = 0; i < 4; i++) {
    int r = row0 + ty * 4 + i;
    if (r < M)
      #pragma unroll
      for (int j = 0; j < 4; j++)
        cs.st(r, col0 + tx * 4 + j, acc[i][j]);
  }
}

// ---------- stage 1 (MFMA, barrier-free): wave = 16 q-rows x full 512 ch ----------
// Swapped QK^T: S = mfma(K_frag, Q_frag) -> lane holds S[key=lg*4+r][q=lr].
// Row-softmax across lanes {lr, lr+16, lr+32, lr+48} via shfl_xor(16,32).
// Defer-rescale (T13, THR=8). P -> per-wave LDS -> A-frag for PV. No __syncthreads.
__global__ __launch_bounds__(256, 2) void stage1_mfma2(const u16* __restrict__ qg,
                                                       const u16* __restrict__ kg,
                                                       const u16* __restrict__ vt,
                                                       u16* __restrict__ xo) {
  __shared__ __align__(16) u16 Pls[4][16][40];   // per-wave P buffer, 80B row stride
  const int tid = threadIdx.x;
  const int wid = tid >> 6, lane = tid & 63;
  const int lr = lane & 15, lg = lane >> 4;
  const int qt = blockIdx.x, f = blockIdx.y, b = blockIdx.z;
  const int q0 = qt * 64 + wid * 16;

  // persistent Q fragments (B-operand): Q[q0+lr][ck*32 + lg*8 .. +7]
  short8 qf[16];
  {
    int qrow = q0 + lr; if (qrow > NN - 1) qrow = NN - 1;
    const u16* qb = qg + ((size_t)b * NN + qrow) * CC + lg * 8;
    #pragma unroll
    for (int ck = 0; ck < 16; ck++) qf[ck] = *(const short8*)(qb + ck * 32);
  }
  f32x4 acc[32];
  #pragma unroll
  for (int j = 0; j < 32; j++) acc[j] = (f32x4){0.f, 0.f, 0.f, 0.f};
  float m = 0.f, l = 0.f;

  const u16* kbase = kg + ((size_t)b * NN + f * PP) * CC;
  const u16* vbase = vt + ((size_t)(b * FF + f)) * CC * PP;   // [c][p]
  u16* Pw = &Pls[wid][0][0];

  for (int ch = 0; ch < 29; ch++) {          // 920 = 28*32 + 24
    const int kk0 = ch * 32;
    const int nv = (ch == 28) ? 24 : 32;
    // ---- QK^T: two 16-key groups, K as A-operand ----
    f32x4 s0 = (f32x4){0.f, 0.f, 0.f, 0.f};
    f32x4 s1 = (f32x4){0.f, 0.f, 0.f, 0.f};
    {
      int key0 = kk0 + lr;                   // always < 920
      int key1 = kk0 + 16 + lr; if (key1 > PP - 1) key1 = PP - 1;
      const u16* kb0 = kbase + (size_t)key0 * CC + lg * 8;
      const u16* kb1 = kbase + (size_t)key1 * CC + lg * 8;
      #pragma unroll
      for (int ck = 0; ck < 16; ck++) {
        short8 k0 = *(const short8*)(kb0 + ck * 32);
        short8 k1 = *(const short8*)(kb1 + ck * 32);
        s0 = __builtin_amdgcn_mfma_f32_16x16x32_bf16(k0, qf[ck], s0, 0, 0, 0);
        s1 = __builtin_amdgcn_mfma_f32_16x16x32_bf16(k1, qf[ck], s1, 0, 0, 0);
      }
    }
    // lane: S[key=kk0+g*16+lg*4+r][q=lr] in s{0,1}[r]
    float pmax = -1e30f;
    #pragma unroll
    for (int r = 0; r < 4; r++) {
      s0[r] *= 0.125f; s1[r] *= 0.125f;
      pmax = fmaxf(pmax, s0[r]);                       // group0 keys all valid
      if (16 + lg * 4 + r < nv) pmax = fmaxf(pmax, s1[r]);
    }
    pmax = fmaxf(pmax, __shfl_xor(pmax, 16));
    pmax = fmaxf(pmax, __shfl_xor(pmax, 32));          // row max (per q=lr)
    if (__any(pmax - m > 8.f)) {                       // deferred rescale (rare)
      float mnew = fmaxf(m, pmax);
      float rs = __expf(m - mnew);
      float rsr[4];
      #pragma unroll
      for (int r = 0; r < 4; r++) rsr[r] = __shfl(rs, lg * 4 + r);
      #pragma unroll
      for (int j = 0; j < 32; j++)
        #pragma unroll
        for (int r = 0; r < 4; r++) acc[j][r] *= rsr[r];
      l *= rs;
      m = mnew;
    }
    // ---- P = exp(S - m) -> bf16 -> per-wave LDS ----
    float psum = 0.f;
    {
      float p0, p1, p2, p3, p4, p5, p6, p7;
      p0 = __expf(s0[0] - m); p1 = __expf(s0[1] - m);
      p2 = __expf(s0[2] - m); p3 = __expf(s0[3] - m);
      p4 = (16 + lg * 4 + 0 < nv) ? __expf(s1[0] - m) : 0.f;
      p5 = (16 + lg * 4 + 1 < nv) ? __expf(s1[1] - m) : 0.f;
      p6 = (16 + lg * 4 + 2 < nv) ? __expf(s1[2] - m) : 0.f;
      p7 = (16 + lg * 4 + 3 < nv) ? __expf(s1[3] - m) : 0.f;
      psum = p0 + p1 + p2 + p3 + p4 + p5 + p6 + p7;
      *(uint2*)&Pw[lr * 40 + lg * 4]      = make_uint2(pack2(p0, p1), pack2(p2, p3));
      *(uint2*)&Pw[lr * 40 + 16 + lg * 4] = make_uint2(pack2(p4, p5), pack2(p6, p7));
    }
    psum += __shfl_xor(psum, 16);
    psum += __shfl_xor(psum, 32);
    l += psum;
    // ---- PV: P as A-frag (LDS), V as B-frag (vt, contiguous in p) ----
    short8 pf = *(const short8*)&Pw[lr * 40 + lg * 8];   // same-wave roundtrip
    int kv0 = kk0 + lg * 8; if (kv0 > PP - 8) kv0 = PP - 8;  // clamped keys have P=0
    const u16* vb = vbase + kv0;
    #pragma unroll
    for (int ct = 0; ct < 32; ct++) {
      short8 vf = *(const short8*)(vb + (size_t)(ct * 16 + lr) * PP);
      acc[ct] = __builtin_amdgcn_mfma_f32_16x16x32_bf16(pf, vf, acc[ct], 0, 0, 0);
    }
  }
  // ---- epilogue: normalize by l, store ----
  float linv = 1.f / l;
  float li[4];
  #pragma unroll
  for (int r = 0; r < 4; r++) li[r] = __shfl(linv, lg * 4 + r);
  #pragma unroll
  for (int ct = 0; ct < 32; ct++) {
    #pragma unroll
    for (int r = 0; r < 4; r++) {
      int q = q0 + lg * 4 + r;
      if (q < NN)
        xo[((size_t)(b * NN + q) * FF + f) * CC + ct * 16 + lr] = f2bf(acc[ct][r] * li[r]);
    }
  }
}

// ---------- fused k2-GEMM + q2 dot -> raw logits (attn2 layout (B,h,N,F)) ----------
__global__ __launch_bounds__(256) void gemm_logits(const u16* __restrict__ xo,
                                                   const u16* __restrict__ q2,
                                                   const float* __restrict__ Wkv2,
                                                   float* __restrict__ attn2) {
  __shared__ __align__(16) float As[16][68];
  __shared__ __align__(16) float Bs[16][68];
  __shared__ float rr[64][17];
  const int tid = threadIdx.x;
  const int tx = tid & 15, ty = tid >> 4;
  const int row0 = blockIdx.y * 64;
  const int h = blockIdx.x;
  const int col0 = h * 64;
  float acc[4][4] = {};
  for (int k0 = 0; k0 < 512; k0 += 16) {
    __syncthreads();
    #pragma unroll
    for (int i = 0; i < 4; i++) {
      int idx = tid + i * 256;
      int ak = idx & 15, ar = idx >> 4;
      int r = row0 + ar;
      As[ak][ar] = (r < 92000) ? bf2f(xo[(size_t)r * CC + k0 + ak]) : 0.f;
    }
    #pragma unroll
    for (int i = 0; i < 4; i++) {
      int idx = tid + i * 256;
      int bk = idx >> 6, bc = idx & 63;
      Bs[bk][bc] = Wkv2[(size_t)(k0 + bk) * 1024 + col0 + bc];
    }
    __syncthreads();
    #pragma unroll
    for (int kk = 0; kk < 16; kk++) {
      float4 av = *(const float4*)&As[kk][ty * 4];
      float4 bv = *(const float4*)&Bs[kk][tx * 4];
      float a[4] = {av.x, av.y, av.z, av.w};
      float bb[4] = {bv.x, bv.y, bv.z, bv.w};
      #pragma unroll
      for (int i = 0; i < 4; i++)
        #pragma unroll
        for (int j = 0; j < 4; j++)
          acc[i][j] = fmaf(a[i], bb[j], acc[i][j]);
    }
  }
  #pragma unroll
  for (int i = 0; i < 4; i++) {
    int r = row0 + ty * 4 + i;
    float p = 0.f;
    if (r < 92000) {
      int q2row = r / 5;
      #pragma unroll
      for (int j = 0; j < 4; j++)
        p += acc[i][j] * bf2f(q2[(size_t)q2row * CC + col0 + tx * 4 + j]);
    }
    rr[ty * 4 + i][tx] = p;
  }
  __syncthreads();
  if (tid < 64) {
    int r = row0 + tid;
    if (r < 92000) {
      float s = 0.f;
      #pragma unroll
      for (int j = 0; j < 16; j++) s += rr[tid][j];
      int b = r / (NN * FF), rem = r - b * (NN * FF);
      int sIdx = rem / FF, f = rem - sIdx * FF;
      attn2[(((size_t)b * 8 + h) * NN + sIdx) * FF + f] = s;
    }
  }
}

// ---------- softmax over F=5, in place on attn2 ----------
__global__ __launch_bounds__(256) void softmax_f5(float* __restrict__ a) {
  int t = blockIdx.x * 256 + threadIdx.x;
  if (t >= NB * 8 * NN) return;
  float* p = a + (size_t)t * FF;
  float l0 = p[0], l1 = p[1], l2 = p[2], l3 = p[3], l4 = p[4];
  float m = fmaxf(fmaxf(fmaxf(l0, l1), fmaxf(l2, l3)), l4);
  float e0 = __expf(l0 - m), e1 = __expf(l1 - m), e2 = __expf(l2 - m),
        e3 = __expf(l3 - m), e4 = __expf(l4 - m);
  float inv = 1.f / (e0 + e1 + e2 + e3 + e4);
  p[0] = e0 * inv; p[1] = e1 * inv; p[2] = e2 * inv; p[3] = e3 * inv; p[4] = e4 * inv;
}

// ---------- fused attn-weighted mix + W_v2 GEMM -> out_pre (bf16) ----------
__global__ __launch_bounds__(256) void gemm_mix(const u16* __restrict__ xo,
                                                const float* __restrict__ attn2,
                                                const float* __restrict__ Wkv2,
                                                u16* __restrict__ outp) {
  __shared__ __align__(16) float As[16][68];
  __shared__ __align__(16) float Bs[16][68];
  __shared__ float aw[64][5];
  const int tid = threadIdx.x;
  const int tx = tid & 15, ty = tid >> 4;
  const int row0 = blockIdx.y * 64;
  const int h = blockIdx.x;
  const int col0 = h * 64;
  if (tid < 64) {
    int r = row0 + tid;
    if (r < 18400) {
      int b = r / NN, s = r - b * NN;
      size_t base = (((size_t)b * 8 + h) * NN + s) * FF;
      #pragma unroll
      for (int f = 0; f < FF; f++) aw[tid][f] = attn2[base + f];
    } else {
      #pragma unroll
      for (int f = 0; f < FF; f++) aw[tid][f] = 0.f;
    }
  }
  float acc[4][4] = {};
  for (int k0 = 0; k0 < 512; k0 += 16) {
    __syncthreads();
    #pragma unroll
    for (int i = 0; i < 4; i++) {
      int idx = tid + i * 256;
      int ak = idx & 15, ar = idx >> 4;
      int r = row0 + ar;
      float aval = 0.f;
      if (r < 18400) {
        size_t xb = ((size_t)r * FF) * CC + k0 + ak;
        #pragma unroll
        for (int f = 0; f < FF; f++)
          aval = fmaf(aw[ar][f], bf2f(xo[xb + (size_t)f * CC]), aval);
      }
      As[ak][ar] = aval;
    }
    #pragma unroll
    for (int i = 0; i < 4; i++) {
      int idx = tid + i * 256;
      int bk = idx >> 6, bc = idx & 63;
      Bs[bk][bc] = Wkv2[(size_t)(k0 + bk) * 1024 + 512 + col0 + bc];
    }
    __syncthreads();
    #pragma unroll
    for (int kk = 0; kk < 16; kk++) {
      float4 av = *(const float4*)&As[kk][ty * 4];
      float4 bv = *(const float4*)&Bs[kk][tx * 4];
      float a[4] = {av.x, av.y, av.z, av.w};
      float bb[4] = {bv.x, bv.y, bv.z, bv.w};
      #pragma unroll
      for (int i = 0; i < 4; i++)
        #pragma unroll
        for (int j = 0; j < 4; j++)
          acc[i][j] = fmaf(a[i], bb[j], acc[i][j]);
    }
  }
  #pragma unroll
  for (int i = 0; i < 4; i++) {
    int r = row0 + ty * 4 + i;
    if (r < 18400)
      #pragma unroll
      for (int j = 0; j < 4; j++)
        outp[(size_t)r * CC + col0 + tx * 4 + j] = f2bf(acc[i][j]);
  }
}

// ---------- sentinel: distinguishes "ws too small" in bench output ----------
__global__ void sentinel_fill(float* o) { o[threadIdx.x] = 777.0f; }

// ---------- launcher ----------
extern "C" void kernel_launch(void* const* d_in, const int* in_sizes, int n_in,
                              void* d_out, int out_size, void* d_ws, size_t ws_size,
                              hipStream_t stream) {
  const float* x     = (const float*)d_in[0];
  const float* Wqkv  = (const float*)d_in[1];
  const float* Wq2   = (const float*)d_in[2];
  const float* Wkv2  = (const float*)d_in[3];
  const float* Wproj = (const float*)d_in[4];
  const float* bproj = (const float*)d_in[5];
  float* out   = (float*)d_out;
  float* attn2 = out + (size_t)PP * NB * FF * CC;

  char* ws = (char*)d_ws;
  const size_t SZ = (size_t)18400 * CC * 2;
  const size_t XO = (size_t)92000 * CC * 2;
  const size_t NEED = 3 * SZ + XO;            // 150,732,800 B
  if (ws_size < NEED) {
    sentinel_fill<<<1, 256, 0, stream>>>(out);
    return;
  }
  u16* q    = (u16*)(ws);
  u16* k    = (u16*)(ws + SZ);
  u16* vt   = (u16*)(ws + 2 * SZ);
  u16* xo   = (u16*)(ws + 3 * SZ);
  u16* q2   = (u16*)(ws);            // alias q (dead after stage1)
  u16* outp = (u16*)(ws + SZ);       // alias k (dead after stage1)

  // 1) QKV projection (v written transposed per (b,f))
  {
    AProvX ap{x}; CSinkQKV cs{q, k, vt};
    gemm64<<<dim3(24, 288), 256, 0, stream>>>(ap, Wqkv, cs, 18400, 512, 1536);
  }
  // 2) stage-1 space attention (MFMA, barrier-free) -> xo (B,N,F,C)
  stage1_mfma2<<<dim3(72, 5, 4), 256, 0, stream>>>(q, k, vt, xo);
  // 3) q2 = diag(xo) @ W_q2 * scale   (overwrites q region)
  {
    AProvDiag ap{xo}; CSinkQ2 cs{q2};
    gemm64<<<dim3(8, 288), 256, 0, stream>>>(ap, Wq2, cs, 18400, 512, 512);
  }
  // 4) fused k2-GEMM + q2 dot -> raw logits into attn2 slice of d_out
  gemm_logits<<<dim3(8, 1438), 256, 0, stream>>>(xo, q2, Wkv2, attn2);
  // 5) softmax over F in place
  softmax_f5<<<(NB * 8 * NN + 255) / 256, 256, 0, stream>>>(attn2);
  // 6) fused mix + W_v2 -> out_pre (overwrites k region)
  gemm_mix<<<dim3(8, 288), 256, 0, stream>>>(xo, attn2, Wkv2, outp);
  // 7) final projection + bias + permute to (P, B*F, C)
  {
    AProvBF ap{outp}; CSinkProj cs{out, bproj};
    gemm64<<<dim3(8, 288), 256, 0, stream>>>(ap, Wproj, cs, 18400, 512, 512);
  }
}

// Round 5
// 1270.421 us; speedup vs baseline: 7.6411x; 2.0649x over previous
//
#include <hip/hip_runtime.h>
#include <hip/hip_bf16.h>
#include <stdint.h>

typedef unsigned short u16;
typedef unsigned int   u32;
typedef __attribute__((ext_vector_type(8))) short short8;
typedef __attribute__((ext_vector_type(4))) float f32x4;

// ---------- bf16 helpers (storage-only bf16, f32 math) ----------
__device__ __forceinline__ float bf2f(u16 a) {
  union { u32 i; float f; } t; t.i = ((u32)a) << 16; return t.f;
}
__device__ __forceinline__ u16 f2bf(float f) {
  union { u32 i; float f; } t; t.f = f;
  u32 r = t.i + 0x7fffu + ((t.i >> 16) & 1u);   // round-nearest-even
  return (u16)(r >> 16);
}
__device__ __forceinline__ u32 pack2(float a, float b) {
  return (u32)f2bf(a) | ((u32)f2bf(b) << 16);
}
__device__ __forceinline__ void unpack8(uint4 u, float* o) {
  union { u32 i; float f; } t;
  t.i = u.x << 16;         o[0] = t.f;
  t.i = u.x & 0xffff0000u; o[1] = t.f;
  t.i = u.y << 16;         o[2] = t.f;
  t.i = u.y & 0xffff0000u; o[3] = t.f;
  t.i = u.z << 16;         o[4] = t.f;
  t.i = u.z & 0xffff0000u; o[5] = t.f;
  t.i = u.w << 16;         o[6] = t.f;
  t.i = u.w & 0xffff0000u; o[7] = t.f;
}

#define NB 4
#define NN 4600
#define FF 5
#define PP 920
#define CC 512

// ---------- weight transpose + bf16: W[512][Nc] f32 -> Wt[Nc][512] bf16 ----------
__global__ __launch_bounds__(256) void wtrans(const float* __restrict__ W,
                                              u16* __restrict__ Wt, int Nc) {
  __shared__ float tile[32][33];
  const int nb = blockIdx.x * 32, kb = blockIdx.y * 32;
  const int tx = threadIdx.x & 31, ty = threadIdx.x >> 5;
  #pragma unroll
  for (int i = 0; i < 4; i++)
    tile[ty + i * 8][tx] = W[(size_t)(kb + ty + i * 8) * Nc + nb + tx];
  __syncthreads();
  #pragma unroll
  for (int i = 0; i < 4; i++)
    Wt[(size_t)(nb + ty + i * 8) * 512 + kb + tx] = f2bf(tile[tx][ty + i * 8]);
}

// ---------- A providers: ldrow16(r, k0, o[16]) ----------
struct AProvX {        // x[n,b,c] f32, row r=(b,n)
  const float* x;
  __device__ __forceinline__ void ldrow16(int r, int k0, float* o) const {
    if (r >= 18400) { for (int j = 0; j < 16; j++) o[j] = 0.f; return; }
    int b = r / NN, n = r - b * NN;
    const float* s = x + ((size_t)n * NB + b) * CC + k0;
    #pragma unroll
    for (int j = 0; j < 4; j++) {
      float4 v = *(const float4*)(s + j * 4);
      o[j * 4] = v.x; o[j * 4 + 1] = v.y; o[j * 4 + 2] = v.z; o[j * 4 + 3] = v.w;
    }
  }
};
struct AProvBF {       // contiguous bf16 rows, stride 512
  const u16* a; int M;
  __device__ __forceinline__ void ldrow16(int r, int k0, float* o) const {
    if (r >= M) { for (int j = 0; j < 16; j++) o[j] = 0.f; return; }
    const u16* s = a + (size_t)r * CC + k0;
    unpack8(*(const uint4*)s, o);
    unpack8(*(const uint4*)(s + 8), o + 8);
  }
};
struct AProvDiag {     // x_diag: row (b,n) -> xo[b,n, n/P, c]
  const u16* xo;
  __device__ __forceinline__ void ldrow16(int r, int k0, float* o) const {
    if (r >= 18400) { for (int j = 0; j < 16; j++) o[j] = 0.f; return; }
    int b = r / NN, n = r - b * NN;
    int f = n / PP;
    const u16* s = xo + (((size_t)b * NN + n) * FF + f) * CC + k0;
    unpack8(*(const uint4*)s, o);
    unpack8(*(const uint4*)(s + 8), o + 8);
  }
};
struct AProvMix {      // mixed_h[r][k] = sum_f attn2[b,h,s,f] * xo[r,f,k]; h = blockIdx.x (BN=64)
  const u16* xo; const float* attn2;
  __device__ __forceinline__ void ldrow16(int r, int k0, float* o) const {
    if (r >= 18400) { for (int j = 0; j < 16; j++) o[j] = 0.f; return; }
    int h = blockIdx.x;
    int b = r / NN, s = r - b * NN;
    const float* aw = attn2 + (((size_t)b * 8 + h) * NN + s) * FF;
    float w[5];
    #pragma unroll
    for (int f = 0; f < FF; f++) w[f] = aw[f];
    #pragma unroll
    for (int j = 0; j < 16; j++) o[j] = 0.f;
    const u16* base = xo + (size_t)r * FF * CC + k0;
    #pragma unroll
    for (int f = 0; f < FF; f++) {
      float t[16];
      const u16* s2 = base + (size_t)f * CC;
      unpack8(*(const uint4*)s2, t);
      unpack8(*(const uint4*)(s2 + 8), t + 8);
      #pragma unroll
      for (int j = 0; j < 16; j++) o[j] = fmaf(w[f], t[j], o[j]);
    }
  }
};

// ---------- C sinks ----------
struct CSinkQKV {      // split 1536 cols: q,k row-major; v stored TRANSPOSED: vt[b][f][c][p]
  u16 *q, *k, *vt;
  __device__ __forceinline__ void st(int r, int c, float val) const {
    u16 hv = f2bf(val);
    if (c < 512)        q[(size_t)r * CC + c] = hv;
    else if (c < 1024)  k[(size_t)r * CC + (c - 512)] = hv;
    else {
      int b = r / NN, n = r - b * NN;
      int f = n / PP, p = n - f * PP;
      vt[(((size_t)(b * FF + f)) * CC + (c - 1024)) * PP + p] = hv;
    }
  }
};
struct CSinkQ2 {       // bf16 * scale (dh^-0.5 = 0.125)
  u16* o;
  __device__ __forceinline__ void st(int r, int c, float v) const {
    o[(size_t)r * CC + c] = f2bf(v * 0.125f);
  }
};
struct CSinkBF512 {    // bf16 row-major 512
  u16* o;
  __device__ __forceinline__ void st(int r, int c, float v) const {
    o[(size_t)r * CC + c] = f2bf(v);
  }
};
struct CSinkProj {     // + bias, scatter to (P, B*F, C) f32
  float* out; const float* bias;
  __device__ __forceinline__ void st(int r, int c, float v) const {
    int b = r / NN, rem = r - b * NN;
    int f = rem / PP, p = rem - f * PP;
    out[((size_t)p * (NB * FF) + b * FF + f) * CC + c] = v + bias[c];
  }
};

// ---------- MFMA GEMM, tile 128x128, 4 waves (2x2 of 64x64), BK=32, K=512 ----------
template<class AP, class CS>
__global__ __launch_bounds__(256) void mgemm128(AP ap, const u16* __restrict__ Bt,
                                                CS cs, int M) {
  __shared__ __align__(16) u16 Al[128][40];   // [row][k], pad 40
  __shared__ __align__(16) u16 Bl[128][40];   // [col][k], pad 40
  const int tid = threadIdx.x;
  const int wid = tid >> 6, lane = tid & 63;
  const int lr = lane & 15, lg = lane >> 4;
  const int wr = wid >> 1, wc = wid & 1;
  const int row0 = blockIdx.y * 128, col0 = blockIdx.x * 128;
  const int srow = tid >> 1, skh = tid & 1;   // staging assignment
  f32x4 acc[4][4];
  #pragma unroll
  for (int i = 0; i < 4; i++)
    #pragma unroll
    for (int j = 0; j < 4; j++) acc[i][j] = (f32x4){0.f, 0.f, 0.f, 0.f};

  for (int k0 = 0; k0 < 512; k0 += 32) {
    __syncthreads();
    { // A tile
      float tmp[16];
      ap.ldrow16(row0 + srow, k0 + skh * 16, tmp);
      u16 tb[16];
      #pragma unroll
      for (int j = 0; j < 16; j++) tb[j] = f2bf(tmp[j]);
      *(uint4*)&Al[srow][skh * 16]     = *(const uint4*)&tb[0];
      *(uint4*)&Al[srow][skh * 16 + 8] = *(const uint4*)&tb[8];
    }
    { // B tile (already bf16, transposed weights)
      const u16* s = Bt + (size_t)(col0 + srow) * 512 + k0 + skh * 16;
      *(uint4*)&Bl[srow][skh * 16]     = *(const uint4*)s;
      *(uint4*)&Bl[srow][skh * 16 + 8] = *(const uint4*)(s + 8);
    }
    __syncthreads();
    short8 afr[4], bfr[4];
    #pragma unroll
    for (int mt = 0; mt < 4; mt++)
      afr[mt] = *(const short8*)&Al[wr * 64 + mt * 16 + lr][lg * 8];
    #pragma unroll
    for (int ct = 0; ct < 4; ct++)
      bfr[ct] = *(const short8*)&Bl[wc * 64 + ct * 16 + lr][lg * 8];
    #pragma unroll
    for (int mt = 0; mt < 4; mt++)
      #pragma unroll
      for (int ct = 0; ct < 4; ct++)
        acc[mt][ct] = __builtin_amdgcn_mfma_f32_16x16x32_bf16(afr[mt], bfr[ct], acc[mt][ct], 0, 0, 0);
  }
  #pragma unroll
  for (int mt = 0; mt < 4; mt++)
    #pragma unroll
    for (int ct = 0; ct < 4; ct++)
      #pragma unroll
      for (int r = 0; r < 4; r++) {
        int rr = row0 + wr * 64 + mt * 16 + lg * 4 + r;
        if (rr < M)
          cs.st(rr, col0 + wc * 64 + ct * 16 + lr, acc[mt][ct][r]);
      }
}

// ---------- MFMA GEMM, tile 128x64, 4 waves (4x1 of 32x64), BK=32 ----------
template<class AP, class CS>
__global__ __launch_bounds__(256) void mgemm64(AP ap, const u16* __restrict__ Bt,
                                               CS cs, int M) {
  __shared__ __align__(16) u16 Al[128][40];
  __shared__ __align__(16) u16 Bl[64][40];
  const int tid = threadIdx.x;
  const int wid = tid >> 6, lane = tid & 63;
  const int lr = lane & 15, lg = lane >> 4;
  const int row0 = blockIdx.y * 128, col0 = blockIdx.x * 64;
  const int srow = tid >> 1, skh = tid & 1;
  const int bcol = tid >> 2, bkq = tid & 3;
  f32x4 acc[2][4];
  #pragma unroll
  for (int i = 0; i < 2; i++)
    #pragma unroll
    for (int j = 0; j < 4; j++) acc[i][j] = (f32x4){0.f, 0.f, 0.f, 0.f};

  for (int k0 = 0; k0 < 512; k0 += 32) {
    __syncthreads();
    {
      float tmp[16];
      ap.ldrow16(row0 + srow, k0 + skh * 16, tmp);
      u16 tb[16];
      #pragma unroll
      for (int j = 0; j < 16; j++) tb[j] = f2bf(tmp[j]);
      *(uint4*)&Al[srow][skh * 16]     = *(const uint4*)&tb[0];
      *(uint4*)&Al[srow][skh * 16 + 8] = *(const uint4*)&tb[8];
    }
    {
      const u16* s = Bt + (size_t)(col0 + bcol) * 512 + k0 + bkq * 8;
      *(uint4*)&Bl[bcol][bkq * 8] = *(const uint4*)s;
    }
    __syncthreads();
    short8 afr[2], bfr[4];
    #pragma unroll
    for (int mt = 0; mt < 2; mt++)
      afr[mt] = *(const short8*)&Al[wid * 32 + mt * 16 + lr][lg * 8];
    #pragma unroll
    for (int ct = 0; ct < 4; ct++)
      bfr[ct] = *(const short8*)&Bl[ct * 16 + lr][lg * 8];
    #pragma unroll
    for (int mt = 0; mt < 2; mt++)
      #pragma unroll
      for (int ct = 0; ct < 4; ct++)
        acc[mt][ct] = __builtin_amdgcn_mfma_f32_16x16x32_bf16(afr[mt], bfr[ct], acc[mt][ct], 0, 0, 0);
  }
  #pragma unroll
  for (int mt = 0; mt < 2; mt++)
    #pragma unroll
    for (int ct = 0; ct < 4; ct++)
      #pragma unroll
      for (int r = 0; r < 4; r++) {
        int rr = row0 + wid * 32 + mt * 16 + lg * 4 + r;
        if (rr < M)
          cs.st(rr, col0 + ct * 16 + lr, acc[mt][ct][r]);
      }
}

// ---------- logits: k2 = xo @ Wk2 (tile 128x128), epilogue: dot with q2, row-reduce, store raw logits ----------
__global__ __launch_bounds__(256) void mgemm_logits(const u16* __restrict__ xo,
                                                    const u16* __restrict__ q2,
                                                    const u16* __restrict__ Wk2t,
                                                    float* __restrict__ attn2) {
  __shared__ __align__(16) u16 Al[128][40];
  __shared__ __align__(16) u16 Bl[128][40];
  const int tid = threadIdx.x;
  const int wid = tid >> 6, lane = tid & 63;
  const int lr = lane & 15, lg = lane >> 4;
  const int wr = wid >> 1, wc = wid & 1;
  const int row0 = blockIdx.y * 128, col0 = blockIdx.x * 128;
  const int srow = tid >> 1, skh = tid & 1;
  f32x4 acc[4][4];
  #pragma unroll
  for (int i = 0; i < 4; i++)
    #pragma unroll
    for (int j = 0; j < 4; j++) acc[i][j] = (f32x4){0.f, 0.f, 0.f, 0.f};

  for (int k0 = 0; k0 < 512; k0 += 32) {
    __syncthreads();
    {
      int r = row0 + srow;
      uint4 v0 = make_uint4(0,0,0,0), v1 = make_uint4(0,0,0,0);
      if (r < 92000) {
        const u16* s = xo + (size_t)r * CC + k0 + skh * 16;
        v0 = *(const uint4*)s; v1 = *(const uint4*)(s + 8);
      }
      *(uint4*)&Al[srow][skh * 16]     = v0;
      *(uint4*)&Al[srow][skh * 16 + 8] = v1;
    }
    {
      const u16* s = Wk2t + (size_t)(col0 + srow) * 512 + k0 + skh * 16;
      *(uint4*)&Bl[srow][skh * 16]     = *(const uint4*)s;
      *(uint4*)&Bl[srow][skh * 16 + 8] = *(const uint4*)(s + 8);
    }
    __syncthreads();
    short8 afr[4], bfr[4];
    #pragma unroll
    for (int mt = 0; mt < 4; mt++)
      afr[mt] = *(const short8*)&Al[wr * 64 + mt * 16 + lr][lg * 8];
    #pragma unroll
    for (int ct = 0; ct < 4; ct++)
      bfr[ct] = *(const short8*)&Bl[wc * 64 + ct * 16 + lr][lg * 8];
    #pragma unroll
    for (int mt = 0; mt < 4; mt++)
      #pragma unroll
      for (int ct = 0; ct < 4; ct++)
        acc[mt][ct] = __builtin_amdgcn_mfma_f32_16x16x32_bf16(afr[mt], bfr[ct], acc[mt][ct], 0, 0, 0);
  }
  // epilogue: logit[r, head] = sum_{c in head's 64} k2[r][c] * q2[r/5][c]
  const int head = blockIdx.x * 2 + wc;
  #pragma unroll
  for (int mt = 0; mt < 4; mt++) {
    float part[4] = {0.f, 0.f, 0.f, 0.f};
    #pragma unroll
    for (int r = 0; r < 4; r++) {
      int rr = row0 + wr * 64 + mt * 16 + lg * 4 + r;
      int rc = rr < 92000 ? rr : 91999;
      const u16* qrow = q2 + (size_t)(rc / 5) * CC + head * 64 + lr;
      #pragma unroll
      for (int ct = 0; ct < 4; ct++)
        part[r] = fmaf(acc[mt][ct][r], bf2f(qrow[ct * 16]), part[r]);
    }
    #pragma unroll
    for (int r = 0; r < 4; r++) {
      float v = part[r];
      v += __shfl_xor(v, 1);
      v += __shfl_xor(v, 2);
      v += __shfl_xor(v, 4);
      v += __shfl_xor(v, 8);
      int rr = row0 + wr * 64 + mt * 16 + lg * 4 + r;
      if (lr == 0 && rr < 92000) {
        int b = rr / (NN * FF), rem = rr - b * (NN * FF);
        int s = rem / FF, f = rem - s * FF;
        attn2[(((size_t)b * 8 + head) * NN + s) * FF + f] = v;
      }
    }
  }
}

// ---------- stage 1 (MFMA, barrier-free): wave = 16 q-rows x full 512 ch ----------
__global__ __launch_bounds__(256, 2) void stage1_mfma2(const u16* __restrict__ qg,
                                                       const u16* __restrict__ kg,
                                                       const u16* __restrict__ vt,
                                                       u16* __restrict__ xo) {
  __shared__ __align__(16) u16 Pls[4][16][40];
  const int tid = threadIdx.x;
  const int wid = tid >> 6, lane = tid & 63;
  const int lr = lane & 15, lg = lane >> 4;
  const int qt = blockIdx.x, f = blockIdx.y, b = blockIdx.z;
  const int q0 = qt * 64 + wid * 16;

  short8 qf[16];
  {
    int qrow = q0 + lr; if (qrow > NN - 1) qrow = NN - 1;
    const u16* qb = qg + ((size_t)b * NN + qrow) * CC + lg * 8;
    #pragma unroll
    for (int ck = 0; ck < 16; ck++) qf[ck] = *(const short8*)(qb + ck * 32);
  }
  f32x4 acc[32];
  #pragma unroll
  for (int j = 0; j < 32; j++) acc[j] = (f32x4){0.f, 0.f, 0.f, 0.f};
  float m = 0.f, l = 0.f;

  const u16* kbase = kg + ((size_t)b * NN + f * PP) * CC;
  const u16* vbase = vt + ((size_t)(b * FF + f)) * CC * PP;
  u16* Pw = &Pls[wid][0][0];

  for (int ch = 0; ch < 29; ch++) {
    const int kk0 = ch * 32;
    const int nv = (ch == 28) ? 24 : 32;
    f32x4 s0 = (f32x4){0.f, 0.f, 0.f, 0.f};
    f32x4 s1 = (f32x4){0.f, 0.f, 0.f, 0.f};
    {
      int key0 = kk0 + lr;
      int key1 = kk0 + 16 + lr; if (key1 > PP - 1) key1 = PP - 1;
      const u16* kb0 = kbase + (size_t)key0 * CC + lg * 8;
      const u16* kb1 = kbase + (size_t)key1 * CC + lg * 8;
      #pragma unroll
      for (int ck = 0; ck < 16; ck++) {
        short8 k0 = *(const short8*)(kb0 + ck * 32);
        short8 k1 = *(const short8*)(kb1 + ck * 32);
        s0 = __builtin_amdgcn_mfma_f32_16x16x32_bf16(k0, qf[ck], s0, 0, 0, 0);
        s1 = __builtin_amdgcn_mfma_f32_16x16x32_bf16(k1, qf[ck], s1, 0, 0, 0);
      }
    }
    float pmax = -1e30f;
    #pragma unroll
    for (int r = 0; r < 4; r++) {
      s0[r] *= 0.125f; s1[r] *= 0.125f;
      pmax = fmaxf(pmax, s0[r]);
      if (16 + lg * 4 + r < nv) pmax = fmaxf(pmax, s1[r]);
    }
    pmax = fmaxf(pmax, __shfl_xor(pmax, 16));
    pmax = fmaxf(pmax, __shfl_xor(pmax, 32));
    if (__any(pmax - m > 8.f)) {
      float mnew = fmaxf(m, pmax);
      float rs = __expf(m - mnew);
      float rsr[4];
      #pragma unroll
      for (int r = 0; r < 4; r++) rsr[r] = __shfl(rs, lg * 4 + r);
      #pragma unroll
      for (int j = 0; j < 32; j++)
        #pragma unroll
        for (int r = 0; r < 4; r++) acc[j][r] *= rsr[r];
      l *= rs;
      m = mnew;
    }
    float psum = 0.f;
    {
      float p0, p1, p2, p3, p4, p5, p6, p7;
      p0 = __expf(s0[0] - m); p1 = __expf(s0[1] - m);
      p2 = __expf(s0[2] - m); p3 = __expf(s0[3] - m);
      p4 = (16 + lg * 4 + 0 < nv) ? __expf(s1[0] - m) : 0.f;
      p5 = (16 + lg * 4 + 1 < nv) ? __expf(s1[1] - m) : 0.f;
      p6 = (16 + lg * 4 + 2 < nv) ? __expf(s1[2] - m) : 0.f;
      p7 = (16 + lg * 4 + 3 < nv) ? __expf(s1[3] - m) : 0.f;
      psum = p0 + p1 + p2 + p3 + p4 + p5 + p6 + p7;
      *(uint2*)&Pw[lr * 40 + lg * 4]      = make_uint2(pack2(p0, p1), pack2(p2, p3));
      *(uint2*)&Pw[lr * 40 + 16 + lg * 4] = make_uint2(pack2(p4, p5), pack2(p6, p7));
    }
    psum += __shfl_xor(psum, 16);
    psum += __shfl_xor(psum, 32);
    l += psum;
    short8 pf = *(const short8*)&Pw[lr * 40 + lg * 8];
    int kv0 = kk0 + lg * 8; if (kv0 > PP - 8) kv0 = PP - 8;
    const u16* vb = vbase + kv0;
    #pragma unroll
    for (int ct = 0; ct < 32; ct++) {
      short8 vf = *(const short8*)(vb + (size_t)(ct * 16 + lr) * PP);
      acc[ct] = __builtin_amdgcn_mfma_f32_16x16x32_bf16(pf, vf, acc[ct], 0, 0, 0);
    }
  }
  float linv = 1.f / l;
  float li[4];
  #pragma unroll
  for (int r = 0; r < 4; r++) li[r] = __shfl(linv, lg * 4 + r);
  #pragma unroll
  for (int ct = 0; ct < 32; ct++) {
    #pragma unroll
    for (int r = 0; r < 4; r++) {
      int q = q0 + lg * 4 + r;
      if (q < NN)
        xo[((size_t)(b * NN + q) * FF + f) * CC + ct * 16 + lr] = f2bf(acc[ct][r] * li[r]);
    }
  }
}

// ---------- softmax over F=5, in place on attn2 ----------
__global__ __launch_bounds__(256) void softmax_f5(float* __restrict__ a) {
  int t = blockIdx.x * 256 + threadIdx.x;
  if (t >= NB * 8 * NN) return;
  float* p = a + (size_t)t * FF;
  float l0 = p[0], l1 = p[1], l2 = p[2], l3 = p[3], l4 = p[4];
  float m = fmaxf(fmaxf(fmaxf(l0, l1), fmaxf(l2, l3)), l4);
  float e0 = __expf(l0 - m), e1 = __expf(l1 - m), e2 = __expf(l2 - m),
        e3 = __expf(l3 - m), e4 = __expf(l4 - m);
  float inv = 1.f / (e0 + e1 + e2 + e3 + e4);
  p[0] = e0 * inv; p[1] = e1 * inv; p[2] = e2 * inv; p[3] = e3 * inv; p[4] = e4 * inv;
}

// ---------- sentinel ----------
__global__ void sentinel_fill(float* o) { o[threadIdx.x] = 777.0f; }

// ---------- launcher ----------
extern "C" void kernel_launch(void* const* d_in, const int* in_sizes, int n_in,
                              void* d_out, int out_size, void* d_ws, size_t ws_size,
                              hipStream_t stream) {
  const float* x     = (const float*)d_in[0];
  const float* Wqkv  = (const float*)d_in[1];
  const float* Wq2   = (const float*)d_in[2];
  const float* Wkv2  = (const float*)d_in[3];
  const float* Wproj = (const float*)d_in[4];
  const float* bproj = (const float*)d_in[5];
  float* out   = (float*)d_out;
  float* attn2 = out + (size_t)PP * NB * FF * CC;

  char* ws = (char*)d_ws;
  const size_t SZ = (size_t)18400 * CC * 2;          // 18.8 MB
  const size_t XO = (size_t)92000 * CC * 2;          // 94.2 MB
  const size_t WT = (size_t)(1536 + 512 + 1024 + 512) * 512 * 2;  // 3.67 MB
  const size_t NEED = 3 * SZ + XO + WT;              // ~154.4 MB
  if (ws_size < NEED) {
    sentinel_fill<<<1, 256, 0, stream>>>(out);
    return;
  }
  u16* q    = (u16*)(ws);
  u16* k    = (u16*)(ws + SZ);
  u16* vt   = (u16*)(ws + 2 * SZ);
  u16* xo   = (u16*)(ws + 3 * SZ);
  u16* wt_qkv  = (u16*)(ws + 3 * SZ + XO);
  u16* wt_q2   = wt_qkv + (size_t)1536 * 512;
  u16* wt_kv2  = wt_q2  + (size_t)512 * 512;
  u16* wt_proj = wt_kv2 + (size_t)1024 * 512;
  u16* q2   = (u16*)(ws);            // alias q (dead after stage1)
  u16* outp = (u16*)(ws + SZ);       // alias k (dead after stage1)

  // 0) weight transpose + bf16 conversion
  wtrans<<<dim3(48, 16), 256, 0, stream>>>(Wqkv,  wt_qkv,  1536);
  wtrans<<<dim3(16, 16), 256, 0, stream>>>(Wq2,   wt_q2,   512);
  wtrans<<<dim3(32, 16), 256, 0, stream>>>(Wkv2,  wt_kv2,  1024);
  wtrans<<<dim3(16, 16), 256, 0, stream>>>(Wproj, wt_proj, 512);

  // 1) QKV projection (MFMA; v written transposed per (b,f))
  {
    AProvX ap{x}; CSinkQKV cs{q, k, vt};
    mgemm128<<<dim3(12, 144), 256, 0, stream>>>(ap, wt_qkv, cs, 18400);
  }
  // 2) stage-1 space attention (MFMA, barrier-free) -> xo (B,N,F,C)
  stage1_mfma2<<<dim3(72, 5, 4), 256, 0, stream>>>(q, k, vt, xo);
  // 3) q2 = diag(xo) @ W_q2 * scale   (overwrites q region)
  {
    AProvDiag ap{xo}; CSinkQ2 cs{q2};
    mgemm128<<<dim3(4, 144), 256, 0, stream>>>(ap, wt_q2, cs, 18400);
  }
  // 4) fused k2-GEMM + q2 dot -> raw logits into attn2 slice of d_out
  mgemm_logits<<<dim3(4, 719), 256, 0, stream>>>(xo, q2, wt_kv2, attn2);
  // 5) softmax over F in place
  softmax_f5<<<(NB * 8 * NN + 255) / 256, 256, 0, stream>>>(attn2);
  // 6) fused mix + W_v2 -> out_pre (overwrites k region); BN=64, head = blockIdx.x
  {
    AProvMix ap{xo, attn2}; CSinkBF512 cs{outp};
    mgemm64<<<dim3(8, 144), 256, 0, stream>>>(ap, wt_kv2 + (size_t)512 * 512, cs, 18400);
  }
  // 7) final projection + bias + permute to (P, B*F, C)
  {
    AProvBF ap{outp, 18400}; CSinkProj cs{out, bproj};
    mgemm128<<<dim3(4, 144), 256, 0, stream>>>(ap, wt_proj, cs, 18400);
  }
}

// Round 6
// 1054.760 us; speedup vs baseline: 9.2034x; 1.2045x over previous
//
#include <hip/hip_runtime.h>
#include <hip/hip_bf16.h>
#include <stdint.h>

typedef unsigned short u16;
typedef unsigned int   u32;
typedef __attribute__((ext_vector_type(8))) short short8;
typedef __attribute__((ext_vector_type(4))) float f32x4;

// ---------- bf16 helpers (storage-only bf16, f32 math) ----------
__device__ __forceinline__ float bf2f(u16 a) {
  union { u32 i; float f; } t; t.i = ((u32)a) << 16; return t.f;
}
__device__ __forceinline__ u16 f2bf(float f) {
  union { u32 i; float f; } t; t.f = f;
  u32 r = t.i + 0x7fffu + ((t.i >> 16) & 1u);   // round-nearest-even
  return (u16)(r >> 16);
}
__device__ __forceinline__ u32 pack2(float a, float b) {
  return (u32)f2bf(a) | ((u32)f2bf(b) << 16);
}
__device__ __forceinline__ void unpack8(uint4 u, float* o) {
  union { u32 i; float f; } t;
  t.i = u.x << 16;         o[0] = t.f;
  t.i = u.x & 0xffff0000u; o[1] = t.f;
  t.i = u.y << 16;         o[2] = t.f;
  t.i = u.y & 0xffff0000u; o[3] = t.f;
  t.i = u.z << 16;         o[4] = t.f;
  t.i = u.z & 0xffff0000u; o[5] = t.f;
  t.i = u.w << 16;         o[6] = t.f;
  t.i = u.w & 0xffff0000u; o[7] = t.f;
}

#define NB 4
#define NN 4600
#define FF 5
#define PP 920
#define CC 512

// ---------- weight transpose + bf16: W[512][Nc] f32 -> Wt[Nc][512] bf16 ----------
__global__ __launch_bounds__(256) void wtrans(const float* __restrict__ W,
                                              u16* __restrict__ Wt, int Nc) {
  __shared__ float tile[32][33];
  const int nb = blockIdx.x * 32, kb = blockIdx.y * 32;
  const int tx = threadIdx.x & 31, ty = threadIdx.x >> 5;
  #pragma unroll
  for (int i = 0; i < 4; i++)
    tile[ty + i * 8][tx] = W[(size_t)(kb + ty + i * 8) * Nc + nb + tx];
  __syncthreads();
  #pragma unroll
  for (int i = 0; i < 4; i++)
    Wt[(size_t)(nb + ty + i * 8) * 512 + kb + tx] = f2bf(tile[tx][ty + i * 8]);
}

// ---------- A providers: ldrow16(r, k0, o[16]) ----------
struct AProvX {        // x[n,b,c] f32, row r=(b,n)
  const float* x;
  __device__ __forceinline__ void ldrow16(int r, int k0, float* o) const {
    if (r >= 18400) { for (int j = 0; j < 16; j++) o[j] = 0.f; return; }
    int b = r / NN, n = r - b * NN;
    const float* s = x + ((size_t)n * NB + b) * CC + k0;
    #pragma unroll
    for (int j = 0; j < 4; j++) {
      float4 v = *(const float4*)(s + j * 4);
      o[j * 4] = v.x; o[j * 4 + 1] = v.y; o[j * 4 + 2] = v.z; o[j * 4 + 3] = v.w;
    }
  }
};
struct AProvBF {       // contiguous bf16 rows, stride 512
  const u16* a; int M;
  __device__ __forceinline__ void ldrow16(int r, int k0, float* o) const {
    if (r >= M) { for (int j = 0; j < 16; j++) o[j] = 0.f; return; }
    const u16* s = a + (size_t)r * CC + k0;
    unpack8(*(const uint4*)s, o);
    unpack8(*(const uint4*)(s + 8), o + 8);
  }
};
struct AProvDiag {     // x_diag: row (b,n) -> xo[b,n, n/P, c]
  const u16* xo;
  __device__ __forceinline__ void ldrow16(int r, int k0, float* o) const {
    if (r >= 18400) { for (int j = 0; j < 16; j++) o[j] = 0.f; return; }
    int b = r / NN, n = r - b * NN;
    int f = n / PP;
    const u16* s = xo + (((size_t)b * NN + n) * FF + f) * CC + k0;
    unpack8(*(const uint4*)s, o);
    unpack8(*(const uint4*)(s + 8), o + 8);
  }
};
struct AProvMix {      // mixed_h[r][k] = sum_f attn2[b,h,s,f] * xo[r,f,k]; h = blockIdx.x (BN=64)
  const u16* xo; const float* attn2;
  __device__ __forceinline__ void ldrow16(int r, int k0, float* o) const {
    if (r >= 18400) { for (int j = 0; j < 16; j++) o[j] = 0.f; return; }
    int h = blockIdx.x;
    int b = r / NN, s = r - b * NN;
    const float* aw = attn2 + (((size_t)b * 8 + h) * NN + s) * FF;
    float w[5];
    #pragma unroll
    for (int f = 0; f < FF; f++) w[f] = aw[f];
    #pragma unroll
    for (int j = 0; j < 16; j++) o[j] = 0.f;
    const u16* base = xo + (size_t)r * FF * CC + k0;
    #pragma unroll
    for (int f = 0; f < FF; f++) {
      float t[16];
      const u16* s2 = base + (size_t)f * CC;
      unpack8(*(const uint4*)s2, t);
      unpack8(*(const uint4*)(s2 + 8), t + 8);
      #pragma unroll
      for (int j = 0; j < 16; j++) o[j] = fmaf(w[f], t[j], o[j]);
    }
  }
};

// ---------- C sinks ----------
struct CSinkQKV {      // split 1536 cols: q,k row-major; v stored TRANSPOSED: vt[b][f][c][p]
  u16 *q, *k, *vt;
  __device__ __forceinline__ void st(int r, int c, float val) const {
    u16 hv = f2bf(val);
    if (c < 512)        q[(size_t)r * CC + c] = hv;
    else if (c < 1024)  k[(size_t)r * CC + (c - 512)] = hv;
    else {
      int b = r / NN, n = r - b * NN;
      int f = n / PP, p = n - f * PP;
      vt[(((size_t)(b * FF + f)) * CC + (c - 1024)) * PP + p] = hv;
    }
  }
};
struct CSinkQ2 {       // bf16 * scale (dh^-0.5 = 0.125)
  u16* o;
  __device__ __forceinline__ void st(int r, int c, float v) const {
    o[(size_t)r * CC + c] = f2bf(v * 0.125f);
  }
};
struct CSinkBF512 {    // bf16 row-major 512
  u16* o;
  __device__ __forceinline__ void st(int r, int c, float v) const {
    o[(size_t)r * CC + c] = f2bf(v);
  }
};
struct CSinkProj {     // + bias, scatter to (P, B*F, C) f32
  float* out; const float* bias;
  __device__ __forceinline__ void st(int r, int c, float v) const {
    int b = r / NN, rem = r - b * NN;
    int f = rem / PP, p = rem - f * PP;
    out[((size_t)p * (NB * FF) + b * FF + f) * CC + c] = v + bias[c];
  }
};

// ---------- MFMA GEMM, tile 128x128, 4 waves (2x2 of 64x64), BK=32, K=512 ----------
template<class AP, class CS>
__global__ __launch_bounds__(256) void mgemm128(AP ap, const u16* __restrict__ Bt,
                                                CS cs, int M) {
  __shared__ __align__(16) u16 Al[128][40];   // [row][k], pad 40
  __shared__ __align__(16) u16 Bl[128][40];   // [col][k], pad 40
  const int tid = threadIdx.x;
  const int wid = tid >> 6, lane = tid & 63;
  const int lr = lane & 15, lg = lane >> 4;
  const int wr = wid >> 1, wc = wid & 1;
  const int row0 = blockIdx.y * 128, col0 = blockIdx.x * 128;
  const int srow = tid >> 1, skh = tid & 1;   // staging assignment
  f32x4 acc[4][4];
  #pragma unroll
  for (int i = 0; i < 4; i++)
    #pragma unroll
    for (int j = 0; j < 4; j++) acc[i][j] = (f32x4){0.f, 0.f, 0.f, 0.f};

  for (int k0 = 0; k0 < 512; k0 += 32) {
    __syncthreads();
    { // A tile
      float tmp[16];
      ap.ldrow16(row0 + srow, k0 + skh * 16, tmp);
      u16 tb[16];
      #pragma unroll
      for (int j = 0; j < 16; j++) tb[j] = f2bf(tmp[j]);
      *(uint4*)&Al[srow][skh * 16]     = *(const uint4*)&tb[0];
      *(uint4*)&Al[srow][skh * 16 + 8] = *(const uint4*)&tb[8];
    }
    { // B tile (already bf16, transposed weights)
      const u16* s = Bt + (size_t)(col0 + srow) * 512 + k0 + skh * 16;
      *(uint4*)&Bl[srow][skh * 16]     = *(const uint4*)s;
      *(uint4*)&Bl[srow][skh * 16 + 8] = *(const uint4*)(s + 8);
    }
    __syncthreads();
    short8 afr[4], bfr[4];
    #pragma unroll
    for (int mt = 0; mt < 4; mt++)
      afr[mt] = *(const short8*)&Al[wr * 64 + mt * 16 + lr][lg * 8];
    #pragma unroll
    for (int ct = 0; ct < 4; ct++)
      bfr[ct] = *(const short8*)&Bl[wc * 64 + ct * 16 + lr][lg * 8];
    #pragma unroll
    for (int mt = 0; mt < 4; mt++)
      #pragma unroll
      for (int ct = 0; ct < 4; ct++)
        acc[mt][ct] = __builtin_amdgcn_mfma_f32_16x16x32_bf16(afr[mt], bfr[ct], acc[mt][ct], 0, 0, 0);
  }
  #pragma unroll
  for (int mt = 0; mt < 4; mt++)
    #pragma unroll
    for (int ct = 0; ct < 4; ct++)
      #pragma unroll
      for (int r = 0; r < 4; r++) {
        int rr = row0 + wr * 64 + mt * 16 + lg * 4 + r;
        if (rr < M)
          cs.st(rr, col0 + wc * 64 + ct * 16 + lr, acc[mt][ct][r]);
      }
}

// ---------- MFMA GEMM, tile 128x64, 4 waves (4x1 of 32x64), BK=32 ----------
template<class AP, class CS>
__global__ __launch_bounds__(256) void mgemm64(AP ap, const u16* __restrict__ Bt,
                                               CS cs, int M) {
  __shared__ __align__(16) u16 Al[128][40];
  __shared__ __align__(16) u16 Bl[64][40];
  const int tid = threadIdx.x;
  const int wid = tid >> 6, lane = tid & 63;
  const int lr = lane & 15, lg = lane >> 4;
  const int row0 = blockIdx.y * 128, col0 = blockIdx.x * 64;
  const int srow = tid >> 1, skh = tid & 1;
  const int bcol = tid >> 2, bkq = tid & 3;
  f32x4 acc[2][4];
  #pragma unroll
  for (int i = 0; i < 2; i++)
    #pragma unroll
    for (int j = 0; j < 4; j++) acc[i][j] = (f32x4){0.f, 0.f, 0.f, 0.f};

  for (int k0 = 0; k0 < 512; k0 += 32) {
    __syncthreads();
    {
      float tmp[16];
      ap.ldrow16(row0 + srow, k0 + skh * 16, tmp);
      u16 tb[16];
      #pragma unroll
      for (int j = 0; j < 16; j++) tb[j] = f2bf(tmp[j]);
      *(uint4*)&Al[srow][skh * 16]     = *(const uint4*)&tb[0];
      *(uint4*)&Al[srow][skh * 16 + 8] = *(const uint4*)&tb[8];
    }
    {
      const u16* s = Bt + (size_t)(col0 + bcol) * 512 + k0 + bkq * 8;
      *(uint4*)&Bl[bcol][bkq * 8] = *(const uint4*)s;
    }
    __syncthreads();
    short8 afr[2], bfr[4];
    #pragma unroll
    for (int mt = 0; mt < 2; mt++)
      afr[mt] = *(const short8*)&Al[wid * 32 + mt * 16 + lr][lg * 8];
    #pragma unroll
    for (int ct = 0; ct < 4; ct++)
      bfr[ct] = *(const short8*)&Bl[ct * 16 + lr][lg * 8];
    #pragma unroll
    for (int mt = 0; mt < 2; mt++)
      #pragma unroll
      for (int ct = 0; ct < 4; ct++)
        acc[mt][ct] = __builtin_amdgcn_mfma_f32_16x16x32_bf16(afr[mt], bfr[ct], acc[mt][ct], 0, 0, 0);
  }
  #pragma unroll
  for (int mt = 0; mt < 2; mt++)
    #pragma unroll
    for (int ct = 0; ct < 4; ct++)
      #pragma unroll
      for (int r = 0; r < 4; r++) {
        int rr = row0 + wid * 32 + mt * 16 + lg * 4 + r;
        if (rr < M)
          cs.st(rr, col0 + ct * 16 + lr, acc[mt][ct][r]);
      }
}

// ---------- logits: k2 = xo @ Wk2 (tile 128x128), epilogue: dot with q2, row-reduce, store raw logits ----------
__global__ __launch_bounds__(256) void mgemm_logits(const u16* __restrict__ xo,
                                                    const u16* __restrict__ q2,
                                                    const u16* __restrict__ Wk2t,
                                                    float* __restrict__ attn2) {
  __shared__ __align__(16) u16 Al[128][40];
  __shared__ __align__(16) u16 Bl[128][40];
  const int tid = threadIdx.x;
  const int wid = tid >> 6, lane = tid & 63;
  const int lr = lane & 15, lg = lane >> 4;
  const int wr = wid >> 1, wc = wid & 1;
  const int row0 = blockIdx.y * 128, col0 = blockIdx.x * 128;
  const int srow = tid >> 1, skh = tid & 1;
  f32x4 acc[4][4];
  #pragma unroll
  for (int i = 0; i < 4; i++)
    #pragma unroll
    for (int j = 0; j < 4; j++) acc[i][j] = (f32x4){0.f, 0.f, 0.f, 0.f};

  for (int k0 = 0; k0 < 512; k0 += 32) {
    __syncthreads();
    {
      int r = row0 + srow;
      uint4 v0 = make_uint4(0,0,0,0), v1 = make_uint4(0,0,0,0);
      if (r < 92000) {
        const u16* s = xo + (size_t)r * CC + k0 + skh * 16;
        v0 = *(const uint4*)s; v1 = *(const uint4*)(s + 8);
      }
      *(uint4*)&Al[srow][skh * 16]     = v0;
      *(uint4*)&Al[srow][skh * 16 + 8] = v1;
    }
    {
      const u16* s = Wk2t + (size_t)(col0 + srow) * 512 + k0 + skh * 16;
      *(uint4*)&Bl[srow][skh * 16]     = *(const uint4*)s;
      *(uint4*)&Bl[srow][skh * 16 + 8] = *(const uint4*)(s + 8);
    }
    __syncthreads();
    short8 afr[4], bfr[4];
    #pragma unroll
    for (int mt = 0; mt < 4; mt++)
      afr[mt] = *(const short8*)&Al[wr * 64 + mt * 16 + lr][lg * 8];
    #pragma unroll
    for (int ct = 0; ct < 4; ct++)
      bfr[ct] = *(const short8*)&Bl[wc * 64 + ct * 16 + lr][lg * 8];
    #pragma unroll
    for (int mt = 0; mt < 4; mt++)
      #pragma unroll
      for (int ct = 0; ct < 4; ct++)
        acc[mt][ct] = __builtin_amdgcn_mfma_f32_16x16x32_bf16(afr[mt], bfr[ct], acc[mt][ct], 0, 0, 0);
  }
  // epilogue: logit[r, head] = sum_{c in head's 64} k2[r][c] * q2[r/5][c]
  const int head = blockIdx.x * 2 + wc;
  #pragma unroll
  for (int mt = 0; mt < 4; mt++) {
    float part[4] = {0.f, 0.f, 0.f, 0.f};
    #pragma unroll
    for (int r = 0; r < 4; r++) {
      int rr = row0 + wr * 64 + mt * 16 + lg * 4 + r;
      int rc = rr < 92000 ? rr : 91999;
      const u16* qrow = q2 + (size_t)(rc / 5) * CC + head * 64 + lr;
      #pragma unroll
      for (int ct = 0; ct < 4; ct++)
        part[r] = fmaf(acc[mt][ct][r], bf2f(qrow[ct * 16]), part[r]);
    }
    #pragma unroll
    for (int r = 0; r < 4; r++) {
      float v = part[r];
      v += __shfl_xor(v, 1);
      v += __shfl_xor(v, 2);
      v += __shfl_xor(v, 4);
      v += __shfl_xor(v, 8);
      int rr = row0 + wr * 64 + mt * 16 + lg * 4 + r;
      if (lr == 0 && rr < 92000) {
        int b = rr / (NN * FF), rem = rr - b * (NN * FF);
        int s = rem / FF, f = rem - s * FF;
        attn2[(((size_t)b * 8 + head) * NN + s) * FF + f] = v;
      }
    }
  }
}

// ---------- stage 1 (MFMA, LDS-staged K/V^T, wave-local softmax) ----------
// Block: 4 waves x 16 q-rows = 64 q, one (b,f). Chunk = 32 keys.
// K chunk staged [32][520] (pad); V^T chunk staged [512][40] (pad) from vt.
// Swapped QK^T (K as A-operand) -> wave-local softmax via shfl_xor(16,32).
// Defer-rescale THR=8. P via per-wave LDS. 2 barriers/chunk.
__global__ __launch_bounds__(256, 2) void stage1_mfma3(const u16* __restrict__ qg,
                                                       const u16* __restrict__ kg,
                                                       const u16* __restrict__ vt,
                                                       u16* __restrict__ xo) {
  __shared__ __align__(16) u16 Kl[32][520];     // 33.3 KB
  __shared__ __align__(16) u16 Vl[512][40];     // 40.0 KB  (V^T: [ch][key])
  __shared__ __align__(16) u16 Pls[4][16][40];  // 5.1 KB
  const int tid = threadIdx.x;
  const int wid = tid >> 6, lane = tid & 63;
  const int lr = lane & 15, lg = lane >> 4;
  const int qt = blockIdx.x, f = blockIdx.y, b = blockIdx.z;
  const int q0 = qt * 64 + wid * 16;

  // persistent Q fragments (B-operand): Q[q0+lr][ck*32 + lg*8 .. +7]
  short8 qf[16];
  {
    int qrow = q0 + lr; if (qrow > NN - 1) qrow = NN - 1;
    const u16* qb = qg + ((size_t)b * NN + qrow) * CC + lg * 8;
    #pragma unroll
    for (int ck = 0; ck < 16; ck++) qf[ck] = *(const short8*)(qb + ck * 32);
  }
  f32x4 acc[32];
  #pragma unroll
  for (int j = 0; j < 32; j++) acc[j] = (f32x4){0.f, 0.f, 0.f, 0.f};
  float m = 0.f, l = 0.f;

  const u16* kbase = kg + ((size_t)b * NN + f * PP) * CC;
  const u16* vbase = vt + ((size_t)(b * FF + f)) * CC * PP;   // [c][p]
  u16* Pw = &Pls[wid][0][0];

  for (int ch = 0; ch < 29; ch++) {          // 920 = 28*32 + 24
    const int kk0 = ch * 32;
    const int nv = (ch == 28) ? 24 : 32;
    __syncthreads();                         // prev compute done before overwrite
    // ---- stage K chunk: 32 keys x 512 ch (32 KB), coalesced ----
    #pragma unroll
    for (int i = 0; i < 8; i++) {
      int idx = i * 256 + tid;
      int row = idx >> 6, c16 = idx & 63;
      int key = kk0 + row; if (key > PP - 1) key = PP - 1;
      *(uint4*)&Kl[row][c16 * 8] = *(const uint4*)(kbase + (size_t)key * CC + c16 * 8);
    }
    // ---- stage V^T chunk: 512 ch x 32 keys (32 KB) from vt ----
    #pragma unroll
    for (int i = 0; i < 8; i++) {
      int idx = i * 256 + tid;
      int chn = idx >> 2, qq = idx & 3;
      int kidx = kk0 + qq * 8; if (kidx > PP - 8) kidx = PP - 8;
      *(uint4*)&Vl[chn][qq * 8] = *(const uint4*)(vbase + (size_t)chn * PP + kidx);
    }
    __syncthreads();                         // staged data visible
    // ---- QK^T: two 16-key groups, K from LDS as A-operand ----
    f32x4 s0 = (f32x4){0.f, 0.f, 0.f, 0.f};
    f32x4 s1 = (f32x4){0.f, 0.f, 0.f, 0.f};
    #pragma unroll
    for (int ck = 0; ck < 16; ck++) {
      short8 k0 = *(const short8*)&Kl[lr][ck * 32 + lg * 8];
      short8 k1 = *(const short8*)&Kl[16 + lr][ck * 32 + lg * 8];
      s0 = __builtin_amdgcn_mfma_f32_16x16x32_bf16(k0, qf[ck], s0, 0, 0, 0);
      s1 = __builtin_amdgcn_mfma_f32_16x16x32_bf16(k1, qf[ck], s1, 0, 0, 0);
    }
    // lane: S[key=kk0+g*16+lg*4+r][q=lr] in s{0,1}[r]
    float pmax = -1e30f;
    #pragma unroll
    for (int r = 0; r < 4; r++) {
      s0[r] *= 0.125f; s1[r] *= 0.125f;
      pmax = fmaxf(pmax, s0[r]);                       // group0 keys all valid
      if (16 + lg * 4 + r < nv) pmax = fmaxf(pmax, s1[r]);
    }
    pmax = fmaxf(pmax, __shfl_xor(pmax, 16));
    pmax = fmaxf(pmax, __shfl_xor(pmax, 32));          // row max (per q=lr)
    if (__any(pmax - m > 8.f)) {                       // deferred rescale (rare)
      float mnew = fmaxf(m, pmax);
      float rs = __expf(m - mnew);
      float rsr[4];
      #pragma unroll
      for (int r = 0; r < 4; r++) rsr[r] = __shfl(rs, lg * 4 + r);
      #pragma unroll
      for (int j = 0; j < 32; j++)
        #pragma unroll
        for (int r = 0; r < 4; r++) acc[j][r] *= rsr[r];
      l *= rs;
      m = mnew;
    }
    // ---- P = exp(S - m) -> bf16 -> per-wave LDS ----
    float psum = 0.f;
    {
      float p0, p1, p2, p3, p4, p5, p6, p7;
      p0 = __expf(s0[0] - m); p1 = __expf(s0[1] - m);
      p2 = __expf(s0[2] - m); p3 = __expf(s0[3] - m);
      p4 = (16 + lg * 4 + 0 < nv) ? __expf(s1[0] - m) : 0.f;
      p5 = (16 + lg * 4 + 1 < nv) ? __expf(s1[1] - m) : 0.f;
      p6 = (16 + lg * 4 + 2 < nv) ? __expf(s1[2] - m) : 0.f;
      p7 = (16 + lg * 4 + 3 < nv) ? __expf(s1[3] - m) : 0.f;
      psum = p0 + p1 + p2 + p3 + p4 + p5 + p6 + p7;
      *(uint2*)&Pw[lr * 40 + lg * 4]      = make_uint2(pack2(p0, p1), pack2(p2, p3));
      *(uint2*)&Pw[lr * 40 + 16 + lg * 4] = make_uint2(pack2(p4, p5), pack2(p6, p7));
    }
    psum += __shfl_xor(psum, 16);
    psum += __shfl_xor(psum, 32);
    l += psum;
    // ---- PV: P as A-frag (per-wave LDS), V^T from LDS as B-frag ----
    short8 pf = *(const short8*)&Pw[lr * 40 + lg * 8];   // same-wave roundtrip
    #pragma unroll
    for (int ct = 0; ct < 32; ct++) {
      short8 vf = *(const short8*)&Vl[ct * 16 + lr][lg * 8];
      acc[ct] = __builtin_amdgcn_mfma_f32_16x16x32_bf16(pf, vf, acc[ct], 0, 0, 0);
    }
  }
  // ---- epilogue: normalize by l, store ----
  float linv = 1.f / l;
  float li[4];
  #pragma unroll
  for (int r = 0; r < 4; r++) li[r] = __shfl(linv, lg * 4 + r);
  #pragma unroll
  for (int ct = 0; ct < 32; ct++) {
    #pragma unroll
    for (int r = 0; r < 4; r++) {
      int q = q0 + lg * 4 + r;
      if (q < NN)
        xo[((size_t)(b * NN + q) * FF + f) * CC + ct * 16 + lr] = f2bf(acc[ct][r] * li[r]);
    }
  }
}

// ---------- softmax over F=5, in place on attn2 ----------
__global__ __launch_bounds__(256) void softmax_f5(float* __restrict__ a) {
  int t = blockIdx.x * 256 + threadIdx.x;
  if (t >= NB * 8 * NN) return;
  float* p = a + (size_t)t * FF;
  float l0 = p[0], l1 = p[1], l2 = p[2], l3 = p[3], l4 = p[4];
  float m = fmaxf(fmaxf(fmaxf(l0, l1), fmaxf(l2, l3)), l4);
  float e0 = __expf(l0 - m), e1 = __expf(l1 - m), e2 = __expf(l2 - m),
        e3 = __expf(l3 - m), e4 = __expf(l4 - m);
  float inv = 1.f / (e0 + e1 + e2 + e3 + e4);
  p[0] = e0 * inv; p[1] = e1 * inv; p[2] = e2 * inv; p[3] = e3 * inv; p[4] = e4 * inv;
}

// ---------- sentinel ----------
__global__ void sentinel_fill(float* o) { o[threadIdx.x] = 777.0f; }

// ---------- launcher ----------
extern "C" void kernel_launch(void* const* d_in, const int* in_sizes, int n_in,
                              void* d_out, int out_size, void* d_ws, size_t ws_size,
                              hipStream_t stream) {
  const float* x     = (const float*)d_in[0];
  const float* Wqkv  = (const float*)d_in[1];
  const float* Wq2   = (const float*)d_in[2];
  const float* Wkv2  = (const float*)d_in[3];
  const float* Wproj = (const float*)d_in[4];
  const float* bproj = (const float*)d_in[5];
  float* out   = (float*)d_out;
  float* attn2 = out + (size_t)PP * NB * FF * CC;

  char* ws = (char*)d_ws;
  const size_t SZ = (size_t)18400 * CC * 2;          // 18.8 MB
  const size_t XO = (size_t)92000 * CC * 2;          // 94.2 MB
  const size_t WT = (size_t)(1536 + 512 + 1024 + 512) * 512 * 2;  // 3.67 MB
  const size_t NEED = 3 * SZ + XO + WT;              // ~154.4 MB
  if (ws_size < NEED) {
    sentinel_fill<<<1, 256, 0, stream>>>(out);
    return;
  }
  u16* q    = (u16*)(ws);
  u16* k    = (u16*)(ws + SZ);
  u16* vt   = (u16*)(ws + 2 * SZ);
  u16* xo   = (u16*)(ws + 3 * SZ);
  u16* wt_qkv  = (u16*)(ws + 3 * SZ + XO);
  u16* wt_q2   = wt_qkv + (size_t)1536 * 512;
  u16* wt_kv2  = wt_q2  + (size_t)512 * 512;
  u16* wt_proj = wt_kv2 + (size_t)1024 * 512;
  u16* q2   = (u16*)(ws);            // alias q (dead after stage1)
  u16* outp = (u16*)(ws + SZ);       // alias k (dead after stage1)

  // 0) weight transpose + bf16 conversion
  wtrans<<<dim3(48, 16), 256, 0, stream>>>(Wqkv,  wt_qkv,  1536);
  wtrans<<<dim3(16, 16), 256, 0, stream>>>(Wq2,   wt_q2,   512);
  wtrans<<<dim3(32, 16), 256, 0, stream>>>(Wkv2,  wt_kv2,  1024);
  wtrans<<<dim3(16, 16), 256, 0, stream>>>(Wproj, wt_proj, 512);

  // 1) QKV projection (MFMA; v written transposed per (b,f))
  {
    AProvX ap{x}; CSinkQKV cs{q, k, vt};
    mgemm128<<<dim3(12, 144), 256, 0, stream>>>(ap, wt_qkv, cs, 18400);
  }
  // 2) stage-1 space attention (MFMA, LDS-staged) -> xo (B,N,F,C)
  stage1_mfma3<<<dim3(72, 5, 4), 256, 0, stream>>>(q, k, vt, xo);
  // 3) q2 = diag(xo) @ W_q2 * scale   (overwrites q region)
  {
    AProvDiag ap{xo}; CSinkQ2 cs{q2};
    mgemm128<<<dim3(4, 144), 256, 0, stream>>>(ap, wt_q2, cs, 18400);
  }
  // 4) fused k2-GEMM + q2 dot -> raw logits into attn2 slice of d_out
  mgemm_logits<<<dim3(4, 719), 256, 0, stream>>>(xo, q2, wt_kv2, attn2);
  // 5) softmax over F in place
  softmax_f5<<<(NB * 8 * NN + 255) / 256, 256, 0, stream>>>(attn2);
  // 6) fused mix + W_v2 -> out_pre (overwrites k region); BN=64, head = blockIdx.x
  {
    AProvMix ap{xo, attn2}; CSinkBF512 cs{outp};
    mgemm64<<<dim3(8, 144), 256, 0, stream>>>(ap, wt_kv2 + (size_t)512 * 512, cs, 18400);
  }
  // 7) final projection + bias + permute to (P, B*F, C)
  {
    AProvBF ap{outp, 18400}; CSinkProj cs{out, bproj};
    mgemm128<<<dim3(4, 144), 256, 0, stream>>>(ap, wt_proj, cs, 18400);
  }
}

// Round 7
// 1006.919 us; speedup vs baseline: 9.6407x; 1.0475x over previous
//
#include <hip/hip_runtime.h>
#include <hip/hip_bf16.h>
#include <stdint.h>

typedef unsigned short u16;
typedef unsigned int   u32;
typedef __attribute__((ext_vector_type(8))) short short8;
typedef __attribute__((ext_vector_type(4))) float f32x4;

// ---------- bf16 helpers (storage-only bf16, f32 math) ----------
__device__ __forceinline__ float bf2f(u16 a) {
  union { u32 i; float f; } t; t.i = ((u32)a) << 16; return t.f;
}
__device__ __forceinline__ u16 f2bf(float f) {
  union { u32 i; float f; } t; t.f = f;
  u32 r = t.i + 0x7fffu + ((t.i >> 16) & 1u);   // round-nearest-even
  return (u16)(r >> 16);
}
__device__ __forceinline__ u32 pack2(float a, float b) {
  return (u32)f2bf(a) | ((u32)f2bf(b) << 16);
}
__device__ __forceinline__ void unpack8(uint4 u, float* o) {
  union { u32 i; float f; } t;
  t.i = u.x << 16;         o[0] = t.f;
  t.i = u.x & 0xffff0000u; o[1] = t.f;
  t.i = u.y << 16;         o[2] = t.f;
  t.i = u.y & 0xffff0000u; o[3] = t.f;
  t.i = u.z << 16;         o[4] = t.f;
  t.i = u.z & 0xffff0000u; o[5] = t.f;
  t.i = u.w << 16;         o[6] = t.f;
  t.i = u.w & 0xffff0000u; o[7] = t.f;
}

// async global->LDS 16B per lane; LDS dest is wave-uniform base + lane*16
__device__ __forceinline__ void gload16(const u16* g, u16* l) {
  __builtin_amdgcn_global_load_lds(
      (const __attribute__((address_space(1))) unsigned int*)g,
      (__attribute__((address_space(3))) unsigned int*)l, 16, 0, 0);
}

#define NB 4
#define NN 4600
#define FF 5
#define PP 920
#define CC 512

// ---------- weight transpose + bf16: W[512][Nc] f32 -> Wt[Nc][512] bf16 ----------
__global__ __launch_bounds__(256) void wtrans(const float* __restrict__ W,
                                              u16* __restrict__ Wt, int Nc) {
  __shared__ float tile[32][33];
  const int nb = blockIdx.x * 32, kb = blockIdx.y * 32;
  const int tx = threadIdx.x & 31, ty = threadIdx.x >> 5;
  #pragma unroll
  for (int i = 0; i < 4; i++)
    tile[ty + i * 8][tx] = W[(size_t)(kb + ty + i * 8) * Nc + nb + tx];
  __syncthreads();
  #pragma unroll
  for (int i = 0; i < 4; i++)
    Wt[(size_t)(nb + ty + i * 8) * 512 + kb + tx] = f2bf(tile[tx][ty + i * 8]);
}

// ---------- A providers: ldrow16(r, k0, o[16]) ----------
struct AProvX {        // x[n,b,c] f32, row r=(b,n)
  const float* x;
  __device__ __forceinline__ void ldrow16(int r, int k0, float* o) const {
    if (r >= 18400) { for (int j = 0; j < 16; j++) o[j] = 0.f; return; }
    int b = r / NN, n = r - b * NN;
    const float* s = x + ((size_t)n * NB + b) * CC + k0;
    #pragma unroll
    for (int j = 0; j < 4; j++) {
      float4 v = *(const float4*)(s + j * 4);
      o[j * 4] = v.x; o[j * 4 + 1] = v.y; o[j * 4 + 2] = v.z; o[j * 4 + 3] = v.w;
    }
  }
};
struct AProvBF {       // contiguous bf16 rows, stride 512
  const u16* a; int M;
  __device__ __forceinline__ void ldrow16(int r, int k0, float* o) const {
    if (r >= M) { for (int j = 0; j < 16; j++) o[j] = 0.f; return; }
    const u16* s = a + (size_t)r * CC + k0;
    unpack8(*(const uint4*)s, o);
    unpack8(*(const uint4*)(s + 8), o + 8);
  }
};
struct AProvDiag {     // x_diag: row (b,n) -> xo[b,n, n/P, c]
  const u16* xo;
  __device__ __forceinline__ void ldrow16(int r, int k0, float* o) const {
    if (r >= 18400) { for (int j = 0; j < 16; j++) o[j] = 0.f; return; }
    int b = r / NN, n = r - b * NN;
    int f = n / PP;
    const u16* s = xo + (((size_t)b * NN + n) * FF + f) * CC + k0;
    unpack8(*(const uint4*)s, o);
    unpack8(*(const uint4*)(s + 8), o + 8);
  }
};
struct AProvMix {      // mixed_h[r][k] = sum_f attn2[b,h,s,f] * xo[r,f,k]; h = blockIdx.x (BN=64)
  const u16* xo; const float* attn2;
  __device__ __forceinline__ void ldrow16(int r, int k0, float* o) const {
    if (r >= 18400) { for (int j = 0; j < 16; j++) o[j] = 0.f; return; }
    int h = blockIdx.x;
    int b = r / NN, s = r - b * NN;
    const float* aw = attn2 + (((size_t)b * 8 + h) * NN + s) * FF;
    float w[5];
    #pragma unroll
    for (int f = 0; f < FF; f++) w[f] = aw[f];
    #pragma unroll
    for (int j = 0; j < 16; j++) o[j] = 0.f;
    const u16* base = xo + (size_t)r * FF * CC + k0;
    #pragma unroll
    for (int f = 0; f < FF; f++) {
      float t[16];
      const u16* s2 = base + (size_t)f * CC;
      unpack8(*(const uint4*)s2, t);
      unpack8(*(const uint4*)(s2 + 8), t + 8);
      #pragma unroll
      for (int j = 0; j < 16; j++) o[j] = fmaf(w[f], t[j], o[j]);
    }
  }
};

// ---------- C sinks ----------
struct CSinkQKV {      // split 1536 cols: q,k row-major; v stored TRANSPOSED: vt[b][f][c][p]
  u16 *q, *k, *vt;
  __device__ __forceinline__ void st(int r, int c, float val) const {
    u16 hv = f2bf(val);
    if (c < 512)        q[(size_t)r * CC + c] = hv;
    else if (c < 1024)  k[(size_t)r * CC + (c - 512)] = hv;
    else {
      int b = r / NN, n = r - b * NN;
      int f = n / PP, p = n - f * PP;
      vt[(((size_t)(b * FF + f)) * CC + (c - 1024)) * PP + p] = hv;
    }
  }
};
struct CSinkQ2 {       // bf16 * scale (dh^-0.5 = 0.125)
  u16* o;
  __device__ __forceinline__ void st(int r, int c, float v) const {
    o[(size_t)r * CC + c] = f2bf(v * 0.125f);
  }
};
struct CSinkBF512 {    // bf16 row-major 512
  u16* o;
  __device__ __forceinline__ void st(int r, int c, float v) const {
    o[(size_t)r * CC + c] = f2bf(v);
  }
};
struct CSinkProj {     // + bias, scatter to (P, B*F, C) f32
  float* out; const float* bias;
  __device__ __forceinline__ void st(int r, int c, float v) const {
    int b = r / NN, rem = r - b * NN;
    int f = rem / PP, p = rem - f * PP;
    out[((size_t)p * (NB * FF) + b * FF + f) * CC + c] = v + bias[c];
  }
};

// ---------- MFMA GEMM, tile 128x128, 4 waves (2x2 of 64x64), BK=32, K=512 ----------
template<class AP, class CS>
__global__ __launch_bounds__(256) void mgemm128(AP ap, const u16* __restrict__ Bt,
                                                CS cs, int M) {
  __shared__ __align__(16) u16 Al[128][40];   // [row][k], pad 40
  __shared__ __align__(16) u16 Bl[128][40];   // [col][k], pad 40
  const int tid = threadIdx.x;
  const int wid = tid >> 6, lane = tid & 63;
  const int lr = lane & 15, lg = lane >> 4;
  const int wr = wid >> 1, wc = wid & 1;
  const int row0 = blockIdx.y * 128, col0 = blockIdx.x * 128;
  const int srow = tid >> 1, skh = tid & 1;   // staging assignment
  f32x4 acc[4][4];
  #pragma unroll
  for (int i = 0; i < 4; i++)
    #pragma unroll
    for (int j = 0; j < 4; j++) acc[i][j] = (f32x4){0.f, 0.f, 0.f, 0.f};

  for (int k0 = 0; k0 < 512; k0 += 32) {
    __syncthreads();
    { // A tile
      float tmp[16];
      ap.ldrow16(row0 + srow, k0 + skh * 16, tmp);
      u16 tb[16];
      #pragma unroll
      for (int j = 0; j < 16; j++) tb[j] = f2bf(tmp[j]);
      *(uint4*)&Al[srow][skh * 16]     = *(const uint4*)&tb[0];
      *(uint4*)&Al[srow][skh * 16 + 8] = *(const uint4*)&tb[8];
    }
    { // B tile (already bf16, transposed weights)
      const u16* s = Bt + (size_t)(col0 + srow) * 512 + k0 + skh * 16;
      *(uint4*)&Bl[srow][skh * 16]     = *(const uint4*)s;
      *(uint4*)&Bl[srow][skh * 16 + 8] = *(const uint4*)(s + 8);
    }
    __syncthreads();
    short8 afr[4], bfr[4];
    #pragma unroll
    for (int mt = 0; mt < 4; mt++)
      afr[mt] = *(const short8*)&Al[wr * 64 + mt * 16 + lr][lg * 8];
    #pragma unroll
    for (int ct = 0; ct < 4; ct++)
      bfr[ct] = *(const short8*)&Bl[wc * 64 + ct * 16 + lr][lg * 8];
    #pragma unroll
    for (int mt = 0; mt < 4; mt++)
      #pragma unroll
      for (int ct = 0; ct < 4; ct++)
        acc[mt][ct] = __builtin_amdgcn_mfma_f32_16x16x32_bf16(afr[mt], bfr[ct], acc[mt][ct], 0, 0, 0);
  }
  #pragma unroll
  for (int mt = 0; mt < 4; mt++)
    #pragma unroll
    for (int ct = 0; ct < 4; ct++)
      #pragma unroll
      for (int r = 0; r < 4; r++) {
        int rr = row0 + wr * 64 + mt * 16 + lg * 4 + r;
        if (rr < M)
          cs.st(rr, col0 + wc * 64 + ct * 16 + lr, acc[mt][ct][r]);
      }
}

// ---------- MFMA GEMM, tile 128x64, 4 waves (4x1 of 32x64), BK=32 ----------
template<class AP, class CS>
__global__ __launch_bounds__(256) void mgemm64(AP ap, const u16* __restrict__ Bt,
                                               CS cs, int M) {
  __shared__ __align__(16) u16 Al[128][40];
  __shared__ __align__(16) u16 Bl[64][40];
  const int tid = threadIdx.x;
  const int wid = tid >> 6, lane = tid & 63;
  const int lr = lane & 15, lg = lane >> 4;
  const int row0 = blockIdx.y * 128, col0 = blockIdx.x * 64;
  const int srow = tid >> 1, skh = tid & 1;
  const int bcol = tid >> 2, bkq = tid & 3;
  f32x4 acc[2][4];
  #pragma unroll
  for (int i = 0; i < 2; i++)
    #pragma unroll
    for (int j = 0; j < 4; j++) acc[i][j] = (f32x4){0.f, 0.f, 0.f, 0.f};

  for (int k0 = 0; k0 < 512; k0 += 32) {
    __syncthreads();
    {
      float tmp[16];
      ap.ldrow16(row0 + srow, k0 + skh * 16, tmp);
      u16 tb[16];
      #pragma unroll
      for (int j = 0; j < 16; j++) tb[j] = f2bf(tmp[j]);
      *(uint4*)&Al[srow][skh * 16]     = *(const uint4*)&tb[0];
      *(uint4*)&Al[srow][skh * 16 + 8] = *(const uint4*)&tb[8];
    }
    {
      const u16* s = Bt + (size_t)(col0 + bcol) * 512 + k0 + bkq * 8;
      *(uint4*)&Bl[bcol][bkq * 8] = *(const uint4*)s;
    }
    __syncthreads();
    short8 afr[2], bfr[4];
    #pragma unroll
    for (int mt = 0; mt < 2; mt++)
      afr[mt] = *(const short8*)&Al[wid * 32 + mt * 16 + lr][lg * 8];
    #pragma unroll
    for (int ct = 0; ct < 4; ct++)
      bfr[ct] = *(const short8*)&Bl[ct * 16 + lr][lg * 8];
    #pragma unroll
    for (int mt = 0; mt < 2; mt++)
      #pragma unroll
      for (int ct = 0; ct < 4; ct++)
        acc[mt][ct] = __builtin_amdgcn_mfma_f32_16x16x32_bf16(afr[mt], bfr[ct], acc[mt][ct], 0, 0, 0);
  }
  #pragma unroll
  for (int mt = 0; mt < 2; mt++)
    #pragma unroll
    for (int ct = 0; ct < 4; ct++)
      #pragma unroll
      for (int r = 0; r < 4; r++) {
        int rr = row0 + wid * 32 + mt * 16 + lg * 4 + r;
        if (rr < M)
          cs.st(rr, col0 + ct * 16 + lr, acc[mt][ct][r]);
      }
}

// ---------- logits: k2 = xo @ Wk2 (tile 128x128), epilogue: dot with q2, row-reduce, store raw logits ----------
__global__ __launch_bounds__(256) void mgemm_logits(const u16* __restrict__ xo,
                                                    const u16* __restrict__ q2,
                                                    const u16* __restrict__ Wk2t,
                                                    float* __restrict__ attn2) {
  __shared__ __align__(16) u16 Al[128][40];
  __shared__ __align__(16) u16 Bl[128][40];
  const int tid = threadIdx.x;
  const int wid = tid >> 6, lane = tid & 63;
  const int lr = lane & 15, lg = lane >> 4;
  const int wr = wid >> 1, wc = wid & 1;
  const int row0 = blockIdx.y * 128, col0 = blockIdx.x * 128;
  const int srow = tid >> 1, skh = tid & 1;
  f32x4 acc[4][4];
  #pragma unroll
  for (int i = 0; i < 4; i++)
    #pragma unroll
    for (int j = 0; j < 4; j++) acc[i][j] = (f32x4){0.f, 0.f, 0.f, 0.f};

  for (int k0 = 0; k0 < 512; k0 += 32) {
    __syncthreads();
    {
      int r = row0 + srow;
      uint4 v0 = make_uint4(0,0,0,0), v1 = make_uint4(0,0,0,0);
      if (r < 92000) {
        const u16* s = xo + (size_t)r * CC + k0 + skh * 16;
        v0 = *(const uint4*)s; v1 = *(const uint4*)(s + 8);
      }
      *(uint4*)&Al[srow][skh * 16]     = v0;
      *(uint4*)&Al[srow][skh * 16 + 8] = v1;
    }
    {
      const u16* s = Wk2t + (size_t)(col0 + srow) * 512 + k0 + skh * 16;
      *(uint4*)&Bl[srow][skh * 16]     = *(const uint4*)s;
      *(uint4*)&Bl[srow][skh * 16 + 8] = *(const uint4*)(s + 8);
    }
    __syncthreads();
    short8 afr[4], bfr[4];
    #pragma unroll
    for (int mt = 0; mt < 4; mt++)
      afr[mt] = *(const short8*)&Al[wr * 64 + mt * 16 + lr][lg * 8];
    #pragma unroll
    for (int ct = 0; ct < 4; ct++)
      bfr[ct] = *(const short8*)&Bl[wc * 64 + ct * 16 + lr][lg * 8];
    #pragma unroll
    for (int mt = 0; mt < 4; mt++)
      #pragma unroll
      for (int ct = 0; ct < 4; ct++)
        acc[mt][ct] = __builtin_amdgcn_mfma_f32_16x16x32_bf16(afr[mt], bfr[ct], acc[mt][ct], 0, 0, 0);
  }
  // epilogue: logit[r, head] = sum_{c in head's 64} k2[r][c] * q2[r/5][c]
  const int head = blockIdx.x * 2 + wc;
  #pragma unroll
  for (int mt = 0; mt < 4; mt++) {
    float part[4] = {0.f, 0.f, 0.f, 0.f};
    #pragma unroll
    for (int r = 0; r < 4; r++) {
      int rr = row0 + wr * 64 + mt * 16 + lg * 4 + r;
      int rc = rr < 92000 ? rr : 91999;
      const u16* qrow = q2 + (size_t)(rc / 5) * CC + head * 64 + lr;
      #pragma unroll
      for (int ct = 0; ct < 4; ct++)
        part[r] = fmaf(acc[mt][ct][r], bf2f(qrow[ct * 16]), part[r]);
    }
    #pragma unroll
    for (int r = 0; r < 4; r++) {
      float v = part[r];
      v += __shfl_xor(v, 1);
      v += __shfl_xor(v, 2);
      v += __shfl_xor(v, 4);
      v += __shfl_xor(v, 8);
      int rr = row0 + wr * 64 + mt * 16 + lg * 4 + r;
      if (lr == 0 && rr < 92000) {
        int b = rr / (NN * FF), rem = rr - b * (NN * FF);
        int s = rem / FF, f = rem - s * FF;
        attn2[(((size_t)b * 8 + head) * NN + s) * FF + f] = v;
      }
    }
  }
}

// ---------- stage 1 (MFMA, double-buffered global_load_lds pipeline) ----------
// Block: 4 waves x 16 q-rows = 64 q, one (b,f). Chunk = 32 keys.
// K LDS: flat [32][512] per buffer, XOR swizzle slot^=(row&7) (pre-swizzled global src).
// V LDS: flat [512][32] per buffer, XOR swizzle slot^=((chn>>1)&3).
// 2-phase: STAGE(next) async -> vmcnt(16) -> barrier -> compute(cur) -> barrier.
__global__ __launch_bounds__(256, 1) void stage1_mfma4(const u16* __restrict__ qg,
                                                       const u16* __restrict__ kg,
                                                       const u16* __restrict__ vt,
                                                       u16* __restrict__ xo) {
  __shared__ __align__(16) u16 KF[2][32 * 512];   // 2 x 32 KB
  __shared__ __align__(16) u16 VF[2][512 * 32];   // 2 x 32 KB
  __shared__ __align__(16) u16 Pls[4][16][40];    // 5 KB
  const int tid = threadIdx.x;
  const int wid = tid >> 6, lane = tid & 63;
  const int lr = lane & 15, lg = lane >> 4;
  const int qt = blockIdx.x, f = blockIdx.y, b = blockIdx.z;
  const int q0 = qt * 64 + wid * 16;

  const u16* kbase = kg + ((size_t)b * NN + f * PP) * CC;
  const u16* vbase = vt + ((size_t)(b * FF + f)) * CC * PP;   // [c][p]
  u16* Pw = &Pls[wid][0][0];

  // V-stage lane mapping constants (per lane, chunk-independent)
  const int vchn_off = lane >> 2;                    // + j*16
  const int vk8 = (lane & 3) ^ ((lane >> 3) & 3);    // swizzled key-group

  // ---- prologue: stage chunk 0 into buffer 0 ----
  {
    #pragma unroll
    for (int c = 0; c < 8; c++) {               // K rows wid*8+c
      int r = wid * 8 + c;
      int key = r;                              // chunk 0: kk0 = 0 (< 920 always)
      const u16* src = kbase + (size_t)key * CC + ((lane ^ (r & 7)) * 8);
      gload16(src, &KF[0][r * 512]);
    }
    #pragma unroll
    for (int c = 0; c < 8; c++) {               // V slot-groups j = wid*8+c
      int j = wid * 8 + c;
      int chn = j * 16 + vchn_off;
      int kidx = vk8 * 8;
      const u16* src = vbase + (size_t)chn * PP + kidx;
      gload16(src, &VF[0][j * 512]);
    }
  }

  // persistent Q fragments (B-operand): Q[q0+lr][ck*32 + lg*8 .. +7]
  short8 qf[16];
  {
    int qrow = q0 + lr; if (qrow > NN - 1) qrow = NN - 1;
    const u16* qb = qg + ((size_t)b * NN + qrow) * CC + lg * 8;
    #pragma unroll
    for (int ck = 0; ck < 16; ck++) qf[ck] = *(const short8*)(qb + ck * 32);
  }
  f32x4 acc[32];
  #pragma unroll
  for (int j = 0; j < 32; j++) acc[j] = (f32x4){0.f, 0.f, 0.f, 0.f};
  float m = 0.f, l = 0.f;

  for (int ch = 0; ch < 29; ch++) {          // 920 = 28*32 + 24
    const int kk0 = ch * 32;
    const int nv = (ch == 28) ? 24 : 32;
    const int cur = ch & 1, nxt = cur ^ 1;
    // ---- stage chunk ch+1 into other buffer (async), then wait for cur ----
    if (ch < 28) {
      const int kk0n = kk0 + 32;
      #pragma unroll
      for (int c = 0; c < 8; c++) {
        int r = wid * 8 + c;
        int key = kk0n + r; if (key > PP - 1) key = PP - 1;
        const u16* src = kbase + (size_t)key * CC + ((lane ^ (r & 7)) * 8);
        gload16(src, &KF[nxt][r * 512]);
      }
      #pragma unroll
      for (int c = 0; c < 8; c++) {
        int j = wid * 8 + c;
        int chn = j * 16 + vchn_off;
        int kidx = kk0n + vk8 * 8; if (kidx > PP - 8) kidx = PP - 8;
        const u16* src = vbase + (size_t)chn * PP + kidx;
        gload16(src, &VF[nxt][j * 512]);
      }
      asm volatile("s_waitcnt vmcnt(16)" ::: "memory");   // cur buffer complete
    } else {
      asm volatile("s_waitcnt vmcnt(0)" ::: "memory");
    }
    __builtin_amdgcn_s_barrier();
    __builtin_amdgcn_sched_barrier(0);
    // ---- QK^T: two 16-key groups, K from LDS (swizzled read) ----
    const u16* Kb = &KF[cur][0];
    const u16* Vb = &VF[cur][0];
    f32x4 s0 = (f32x4){0.f, 0.f, 0.f, 0.f};
    f32x4 s1 = (f32x4){0.f, 0.f, 0.f, 0.f};
    #pragma unroll
    for (int ck = 0; ck < 16; ck++) {
      int sl0 = ((lr * 64 + ck * 4 + lg) ^ (lr & 7)) * 8;
      int sl1 = (((16 + lr) * 64 + ck * 4 + lg) ^ (lr & 7)) * 8;
      short8 k0 = *(const short8*)&Kb[sl0];
      short8 k1 = *(const short8*)&Kb[sl1];
      s0 = __builtin_amdgcn_mfma_f32_16x16x32_bf16(k0, qf[ck], s0, 0, 0, 0);
      s1 = __builtin_amdgcn_mfma_f32_16x16x32_bf16(k1, qf[ck], s1, 0, 0, 0);
    }
    // lane: S[key=kk0+g*16+lg*4+r][q=lr] in s{0,1}[r]
    float pmax = -1e30f;
    #pragma unroll
    for (int r = 0; r < 4; r++) {
      s0[r] *= 0.125f; s1[r] *= 0.125f;
      pmax = fmaxf(pmax, s0[r]);                       // group0 keys all valid
      if (16 + lg * 4 + r < nv) pmax = fmaxf(pmax, s1[r]);
    }
    pmax = fmaxf(pmax, __shfl_xor(pmax, 16));
    pmax = fmaxf(pmax, __shfl_xor(pmax, 32));          // row max (per q=lr)
    if (__any(pmax - m > 8.f)) {                       // deferred rescale (rare)
      float mnew = fmaxf(m, pmax);
      float rs = __expf(m - mnew);
      float rsr[4];
      #pragma unroll
      for (int r = 0; r < 4; r++) rsr[r] = __shfl(rs, lg * 4 + r);
      #pragma unroll
      for (int j = 0; j < 32; j++)
        #pragma unroll
        for (int r = 0; r < 4; r++) acc[j][r] *= rsr[r];
      l *= rs;
      m = mnew;
    }
    // ---- P = exp(S - m) -> bf16 -> per-wave LDS ----
    float psum = 0.f;
    {
      float p0, p1, p2, p3, p4, p5, p6, p7;
      p0 = __expf(s0[0] - m); p1 = __expf(s0[1] - m);
      p2 = __expf(s0[2] - m); p3 = __expf(s0[3] - m);
      p4 = (16 + lg * 4 + 0 < nv) ? __expf(s1[0] - m) : 0.f;
      p5 = (16 + lg * 4 + 1 < nv) ? __expf(s1[1] - m) : 0.f;
      p6 = (16 + lg * 4 + 2 < nv) ? __expf(s1[2] - m) : 0.f;
      p7 = (16 + lg * 4 + 3 < nv) ? __expf(s1[3] - m) : 0.f;
      psum = p0 + p1 + p2 + p3 + p4 + p5 + p6 + p7;
      *(uint2*)&Pw[lr * 40 + lg * 4]      = make_uint2(pack2(p0, p1), pack2(p2, p3));
      *(uint2*)&Pw[lr * 40 + 16 + lg * 4] = make_uint2(pack2(p4, p5), pack2(p6, p7));
    }
    psum += __shfl_xor(psum, 16);
    psum += __shfl_xor(psum, 32);
    l += psum;
    // ---- PV: P as A-frag (per-wave LDS), V^T from LDS (swizzled read) ----
    short8 pf = *(const short8*)&Pw[lr * 40 + lg * 8];   // same-wave roundtrip
    #pragma unroll
    for (int ct = 0; ct < 32; ct++) {
      int chn = ct * 16 + lr;
      int sl = ((chn * 4 + lg) ^ ((chn >> 1) & 3)) * 8;
      short8 vf = *(const short8*)&Vb[sl];
      acc[ct] = __builtin_amdgcn_mfma_f32_16x16x32_bf16(pf, vf, acc[ct], 0, 0, 0);
    }
    __builtin_amdgcn_s_barrier();              // all waves done reading cur
    __builtin_amdgcn_sched_barrier(0);         // keep next STAGE below this point
  }
  // ---- epilogue: normalize by l, store ----
  float linv = 1.f / l;
  float li[4];
  #pragma unroll
  for (int r = 0; r < 4; r++) li[r] = __shfl(linv, lg * 4 + r);
  #pragma unroll
  for (int ct = 0; ct < 32; ct++) {
    #pragma unroll
    for (int r = 0; r < 4; r++) {
      int q = q0 + lg * 4 + r;
      if (q < NN)
        xo[((size_t)(b * NN + q) * FF + f) * CC + ct * 16 + lr] = f2bf(acc[ct][r] * li[r]);
    }
  }
}

// ---------- softmax over F=5, in place on attn2 ----------
__global__ __launch_bounds__(256) void softmax_f5(float* __restrict__ a) {
  int t = blockIdx.x * 256 + threadIdx.x;
  if (t >= NB * 8 * NN) return;
  float* p = a + (size_t)t * FF;
  float l0 = p[0], l1 = p[1], l2 = p[2], l3 = p[3], l4 = p[4];
  float m = fmaxf(fmaxf(fmaxf(l0, l1), fmaxf(l2, l3)), l4);
  float e0 = __expf(l0 - m), e1 = __expf(l1 - m), e2 = __expf(l2 - m),
        e3 = __expf(l3 - m), e4 = __expf(l4 - m);
  float inv = 1.f / (e0 + e1 + e2 + e3 + e4);
  p[0] = e0 * inv; p[1] = e1 * inv; p[2] = e2 * inv; p[3] = e3 * inv; p[4] = e4 * inv;
}

// ---------- sentinel ----------
__global__ void sentinel_fill(float* o) { o[threadIdx.x] = 777.0f; }

// ---------- launcher ----------
extern "C" void kernel_launch(void* const* d_in, const int* in_sizes, int n_in,
                              void* d_out, int out_size, void* d_ws, size_t ws_size,
                              hipStream_t stream) {
  const float* x     = (const float*)d_in[0];
  const float* Wqkv  = (const float*)d_in[1];
  const float* Wq2   = (const float*)d_in[2];
  const float* Wkv2  = (const float*)d_in[3];
  const float* Wproj = (const float*)d_in[4];
  const float* bproj = (const float*)d_in[5];
  float* out   = (float*)d_out;
  float* attn2 = out + (size_t)PP * NB * FF * CC;

  char* ws = (char*)d_ws;
  const size_t SZ = (size_t)18400 * CC * 2;          // 18.8 MB
  const size_t XO = (size_t)92000 * CC * 2;          // 94.2 MB
  const size_t WT = (size_t)(1536 + 512 + 1024 + 512) * 512 * 2;  // 3.67 MB
  const size_t NEED = 3 * SZ + XO + WT;              // ~154.4 MB
  if (ws_size < NEED) {
    sentinel_fill<<<1, 256, 0, stream>>>(out);
    return;
  }
  u16* q    = (u16*)(ws);
  u16* k    = (u16*)(ws + SZ);
  u16* vt   = (u16*)(ws + 2 * SZ);
  u16* xo   = (u16*)(ws + 3 * SZ);
  u16* wt_qkv  = (u16*)(ws + 3 * SZ + XO);
  u16* wt_q2   = wt_qkv + (size_t)1536 * 512;
  u16* wt_kv2  = wt_q2  + (size_t)512 * 512;
  u16* wt_proj = wt_kv2 + (size_t)1024 * 512;
  u16* q2   = (u16*)(ws);            // alias q (dead after stage1)
  u16* outp = (u16*)(ws + SZ);       // alias k (dead after stage1)

  // 0) weight transpose + bf16 conversion
  wtrans<<<dim3(48, 16), 256, 0, stream>>>(Wqkv,  wt_qkv,  1536);
  wtrans<<<dim3(16, 16), 256, 0, stream>>>(Wq2,   wt_q2,   512);
  wtrans<<<dim3(32, 16), 256, 0, stream>>>(Wkv2,  wt_kv2,  1024);
  wtrans<<<dim3(16, 16), 256, 0, stream>>>(Wproj, wt_proj, 512);

  // 1) QKV projection (MFMA; v written transposed per (b,f))
  {
    AProvX ap{x}; CSinkQKV cs{q, k, vt};
    mgemm128<<<dim3(12, 144), 256, 0, stream>>>(ap, wt_qkv, cs, 18400);
  }
  // 2) stage-1 space attention (MFMA, async double-buffered) -> xo (B,N,F,C)
  stage1_mfma4<<<dim3(72, 5, 4), 256, 0, stream>>>(q, k, vt, xo);
  // 3) q2 = diag(xo) @ W_q2 * scale   (overwrites q region)
  {
    AProvDiag ap{xo}; CSinkQ2 cs{q2};
    mgemm128<<<dim3(4, 144), 256, 0, stream>>>(ap, wt_q2, cs, 18400);
  }
  // 4) fused k2-GEMM + q2 dot -> raw logits into attn2 slice of d_out
  mgemm_logits<<<dim3(4, 719), 256, 0, stream>>>(xo, q2, wt_kv2, attn2);
  // 5) softmax over F in place
  softmax_f5<<<(NB * 8 * NN + 255) / 256, 256, 0, stream>>>(attn2);
  // 6) fused mix + W_v2 -> out_pre (overwrites k region); BN=64, head = blockIdx.x
  {
    AProvMix ap{xo, attn2}; CSinkBF512 cs{outp};
    mgemm64<<<dim3(8, 144), 256, 0, stream>>>(ap, wt_kv2 + (size_t)512 * 512, cs, 18400);
  }
  // 7) final projection + bias + permute to (P, B*F, C)
  {
    AProvBF ap{outp, 18400}; CSinkProj cs{out, bproj};
    mgemm128<<<dim3(4, 144), 256, 0, stream>>>(ap, wt_proj, cs, 18400);
  }
}

// Round 9
// 881.946 us; speedup vs baseline: 11.0068x; 1.1417x over previous
//
#include <hip/hip_runtime.h>
#include <hip/hip_bf16.h>
#include <stdint.h>

typedef unsigned short u16;
typedef unsigned int   u32;
typedef __attribute__((ext_vector_type(8))) short short8;
typedef __attribute__((ext_vector_type(4))) short s16x4;
typedef __attribute__((ext_vector_type(4))) float f32x4;

// ---------- 16x16x16 bf16 MFMA: builtin if available (device pass), else inline asm ----------
__device__ __forceinline__ f32x4 mfma16(s16x4 a, s16x4 b, f32x4 c) {
#if defined(__HIP_DEVICE_COMPILE__)
#if __has_builtin(__builtin_amdgcn_mfma_f32_16x16x16bf16_1k)
  return __builtin_amdgcn_mfma_f32_16x16x16bf16_1k(a, b, c, 0, 0, 0);
#else
  // s_nop covers VALU-write -> MFMA-read hazard (no compiler hazard handling in asm)
  asm volatile("s_nop 1\n\tv_mfma_f32_16x16x16_bf16 %0, %1, %2, %0"
               : "+v"(c) : "v"(a), "v"(b));
  return c;
#endif
#else
  return c;  // host pass: never executed
#endif
}

// ---------- bf16 helpers (storage-only bf16, f32 math) ----------
__device__ __forceinline__ float bf2f(u16 a) {
  union { u32 i; float f; } t; t.i = ((u32)a) << 16; return t.f;
}
__device__ __forceinline__ u16 f2bf(float f) {
  union { u32 i; float f; } t; t.f = f;
  u32 r = t.i + 0x7fffu + ((t.i >> 16) & 1u);   // round-nearest-even
  return (u16)(r >> 16);
}
__device__ __forceinline__ u32 pack2(float a, float b) {
  return (u32)f2bf(a) | ((u32)f2bf(b) << 16);
}
__device__ __forceinline__ void unpack8(uint4 u, float* o) {
  union { u32 i; float f; } t;
  t.i = u.x << 16;         o[0] = t.f;
  t.i = u.x & 0xffff0000u; o[1] = t.f;
  t.i = u.y << 16;         o[2] = t.f;
  t.i = u.y & 0xffff0000u; o[3] = t.f;
  t.i = u.z << 16;         o[4] = t.f;
  t.i = u.z & 0xffff0000u; o[5] = t.f;
  t.i = u.w << 16;         o[6] = t.f;
  t.i = u.w & 0xffff0000u; o[7] = t.f;
}

// async global->LDS 16B per lane; LDS dest is wave-uniform base + lane*16
__device__ __forceinline__ void gload16(const u16* g, u16* l) {
  __builtin_amdgcn_global_load_lds(
      (const __attribute__((address_space(1))) unsigned int*)g,
      (__attribute__((address_space(3))) unsigned int*)l, 16, 0, 0);
}

#define NB 4
#define NN 4600
#define FF 5
#define PP 920
#define CC 512

// ---------- weight transpose + bf16: W[512][Nc] f32 -> Wt[Nc][512] bf16 ----------
__global__ __launch_bounds__(256) void wtrans(const float* __restrict__ W,
                                              u16* __restrict__ Wt, int Nc) {
  __shared__ float tile[32][33];
  const int nb = blockIdx.x * 32, kb = blockIdx.y * 32;
  const int tx = threadIdx.x & 31, ty = threadIdx.x >> 5;
  #pragma unroll
  for (int i = 0; i < 4; i++)
    tile[ty + i * 8][tx] = W[(size_t)(kb + ty + i * 8) * Nc + nb + tx];
  __syncthreads();
  #pragma unroll
  for (int i = 0; i < 4; i++)
    Wt[(size_t)(nb + ty + i * 8) * 512 + kb + tx] = f2bf(tile[tx][ty + i * 8]);
}

// ---------- A providers: ldrow16(r, k0, o[16]) ----------
struct AProvX {        // x[n,b,c] f32, row r=(b,n)
  const float* x;
  __device__ __forceinline__ void ldrow16(int r, int k0, float* o) const {
    if (r >= 18400) { for (int j = 0; j < 16; j++) o[j] = 0.f; return; }
    int b = r / NN, n = r - b * NN;
    const float* s = x + ((size_t)n * NB + b) * CC + k0;
    #pragma unroll
    for (int j = 0; j < 4; j++) {
      float4 v = *(const float4*)(s + j * 4);
      o[j * 4] = v.x; o[j * 4 + 1] = v.y; o[j * 4 + 2] = v.z; o[j * 4 + 3] = v.w;
    }
  }
};
struct AProvBF {       // contiguous bf16 rows, stride 512
  const u16* a; int M;
  __device__ __forceinline__ void ldrow16(int r, int k0, float* o) const {
    if (r >= M) { for (int j = 0; j < 16; j++) o[j] = 0.f; return; }
    const u16* s = a + (size_t)r * CC + k0;
    unpack8(*(const uint4*)s, o);
    unpack8(*(const uint4*)(s + 8), o + 8);
  }
};
struct AProvDiag {     // x_diag: row (b,n) -> xo[b,n, n/P, c]
  const u16* xo;
  __device__ __forceinline__ void ldrow16(int r, int k0, float* o) const {
    if (r >= 18400) { for (int j = 0; j < 16; j++) o[j] = 0.f; return; }
    int b = r / NN, n = r - b * NN;
    int f = n / PP;
    const u16* s = xo + (((size_t)b * NN + n) * FF + f) * CC + k0;
    unpack8(*(const uint4*)s, o);
    unpack8(*(const uint4*)(s + 8), o + 8);
  }
};
struct AProvMix {      // mixed_h[r][k] = sum_f attn2[b,h,s,f] * xo[r,f,k]; h = blockIdx.x (BN=64)
  const u16* xo; const float* attn2;
  __device__ __forceinline__ void ldrow16(int r, int k0, float* o) const {
    if (r >= 18400) { for (int j = 0; j < 16; j++) o[j] = 0.f; return; }
    int h = blockIdx.x;
    int b = r / NN, s = r - b * NN;
    const float* aw = attn2 + (((size_t)b * 8 + h) * NN + s) * FF;
    float w[5];
    #pragma unroll
    for (int f = 0; f < FF; f++) w[f] = aw[f];
    #pragma unroll
    for (int j = 0; j < 16; j++) o[j] = 0.f;
    const u16* base = xo + (size_t)r * FF * CC + k0;
    #pragma unroll
    for (int f = 0; f < FF; f++) {
      float t[16];
      const u16* s2 = base + (size_t)f * CC;
      unpack8(*(const uint4*)s2, t);
      unpack8(*(const uint4*)(s2 + 8), t + 8);
      #pragma unroll
      for (int j = 0; j < 16; j++) o[j] = fmaf(w[f], t[j], o[j]);
    }
  }
};

// ---------- C sinks ----------
struct CSinkQKV {      // split 1536 cols: q,k row-major; v stored TRANSPOSED: vt[b][f][c][p]
  u16 *q, *k, *vt;
  __device__ __forceinline__ void st(int r, int c, float val) const {
    u16 hv = f2bf(val);
    if (c < 512)        q[(size_t)r * CC + c] = hv;
    else if (c < 1024)  k[(size_t)r * CC + (c - 512)] = hv;
    else {
      int b = r / NN, n = r - b * NN;
      int f = n / PP, p = n - f * PP;
      vt[(((size_t)(b * FF + f)) * CC + (c - 1024)) * PP + p] = hv;
    }
  }
};
struct CSinkQ2 {       // bf16 * scale (dh^-0.5 = 0.125)
  u16* o;
  __device__ __forceinline__ void st(int r, int c, float v) const {
    o[(size_t)r * CC + c] = f2bf(v * 0.125f);
  }
};
struct CSinkBF512 {    // bf16 row-major 512
  u16* o;
  __device__ __forceinline__ void st(int r, int c, float v) const {
    o[(size_t)r * CC + c] = f2bf(v);
  }
};
struct CSinkProj {     // + bias, scatter to (P, B*F, C) f32
  float* out; const float* bias;
  __device__ __forceinline__ void st(int r, int c, float v) const {
    int b = r / NN, rem = r - b * NN;
    int f = rem / PP, p = rem - f * PP;
    out[((size_t)p * (NB * FF) + b * FF + f) * CC + c] = v + bias[c];
  }
};

// ---------- MFMA GEMM, tile 128x128, 4 waves (2x2 of 64x64), BK=32, K=512 ----------
template<class AP, class CS>
__global__ __launch_bounds__(256) void mgemm128(AP ap, const u16* __restrict__ Bt,
                                                CS cs, int M) {
  __shared__ __align__(16) u16 Al[128][40];   // [row][k], pad 40
  __shared__ __align__(16) u16 Bl[128][40];   // [col][k], pad 40
  const int tid = threadIdx.x;
  const int wid = tid >> 6, lane = tid & 63;
  const int lr = lane & 15, lg = lane >> 4;
  const int wr = wid >> 1, wc = wid & 1;
  const int row0 = blockIdx.y * 128, col0 = blockIdx.x * 128;
  const int srow = tid >> 1, skh = tid & 1;   // staging assignment
  f32x4 acc[4][4];
  #pragma unroll
  for (int i = 0; i < 4; i++)
    #pragma unroll
    for (int j = 0; j < 4; j++) acc[i][j] = (f32x4){0.f, 0.f, 0.f, 0.f};

  for (int k0 = 0; k0 < 512; k0 += 32) {
    __syncthreads();
    { // A tile
      float tmp[16];
      ap.ldrow16(row0 + srow, k0 + skh * 16, tmp);
      u16 tb[16];
      #pragma unroll
      for (int j = 0; j < 16; j++) tb[j] = f2bf(tmp[j]);
      *(uint4*)&Al[srow][skh * 16]     = *(const uint4*)&tb[0];
      *(uint4*)&Al[srow][skh * 16 + 8] = *(const uint4*)&tb[8];
    }
    { // B tile (already bf16, transposed weights)
      const u16* s = Bt + (size_t)(col0 + srow) * 512 + k0 + skh * 16;
      *(uint4*)&Bl[srow][skh * 16]     = *(const uint4*)s;
      *(uint4*)&Bl[srow][skh * 16 + 8] = *(const uint4*)(s + 8);
    }
    __syncthreads();
    short8 afr[4], bfr[4];
    #pragma unroll
    for (int mt = 0; mt < 4; mt++)
      afr[mt] = *(const short8*)&Al[wr * 64 + mt * 16 + lr][lg * 8];
    #pragma unroll
    for (int ct = 0; ct < 4; ct++)
      bfr[ct] = *(const short8*)&Bl[wc * 64 + ct * 16 + lr][lg * 8];
    #pragma unroll
    for (int mt = 0; mt < 4; mt++)
      #pragma unroll
      for (int ct = 0; ct < 4; ct++)
        acc[mt][ct] = __builtin_amdgcn_mfma_f32_16x16x32_bf16(afr[mt], bfr[ct], acc[mt][ct], 0, 0, 0);
  }
  #pragma unroll
  for (int mt = 0; mt < 4; mt++)
    #pragma unroll
    for (int ct = 0; ct < 4; ct++)
      #pragma unroll
      for (int r = 0; r < 4; r++) {
        int rr = row0 + wr * 64 + mt * 16 + lg * 4 + r;
        if (rr < M)
          cs.st(rr, col0 + wc * 64 + ct * 16 + lr, acc[mt][ct][r]);
      }
}

// ---------- MFMA GEMM, tile 128x64, 4 waves (4x1 of 32x64), BK=32 ----------
template<class AP, class CS>
__global__ __launch_bounds__(256) void mgemm64(AP ap, const u16* __restrict__ Bt,
                                               CS cs, int M) {
  __shared__ __align__(16) u16 Al[128][40];
  __shared__ __align__(16) u16 Bl[64][40];
  const int tid = threadIdx.x;
  const int wid = tid >> 6, lane = tid & 63;
  const int lr = lane & 15, lg = lane >> 4;
  const int row0 = blockIdx.y * 128, col0 = blockIdx.x * 64;
  const int srow = tid >> 1, skh = tid & 1;
  const int bcol = tid >> 2, bkq = tid & 3;
  f32x4 acc[2][4];
  #pragma unroll
  for (int i = 0; i < 2; i++)
    #pragma unroll
    for (int j = 0; j < 4; j++) acc[i][j] = (f32x4){0.f, 0.f, 0.f, 0.f};

  for (int k0 = 0; k0 < 512; k0 += 32) {
    __syncthreads();
    {
      float tmp[16];
      ap.ldrow16(row0 + srow, k0 + skh * 16, tmp);
      u16 tb[16];
      #pragma unroll
      for (int j = 0; j < 16; j++) tb[j] = f2bf(tmp[j]);
      *(uint4*)&Al[srow][skh * 16]     = *(const uint4*)&tb[0];
      *(uint4*)&Al[srow][skh * 16 + 8] = *(const uint4*)&tb[8];
    }
    {
      const u16* s = Bt + (size_t)(col0 + bcol) * 512 + k0 + bkq * 8;
      *(uint4*)&Bl[bcol][bkq * 8] = *(const uint4*)s;
    }
    __syncthreads();
    short8 afr[2], bfr[4];
    #pragma unroll
    for (int mt = 0; mt < 2; mt++)
      afr[mt] = *(const short8*)&Al[wid * 32 + mt * 16 + lr][lg * 8];
    #pragma unroll
    for (int ct = 0; ct < 4; ct++)
      bfr[ct] = *(const short8*)&Bl[ct * 16 + lr][lg * 8];
    #pragma unroll
    for (int mt = 0; mt < 2; mt++)
      #pragma unroll
      for (int ct = 0; ct < 4; ct++)
        acc[mt][ct] = __builtin_amdgcn_mfma_f32_16x16x32_bf16(afr[mt], bfr[ct], acc[mt][ct], 0, 0, 0);
  }
  #pragma unroll
  for (int mt = 0; mt < 2; mt++)
    #pragma unroll
    for (int ct = 0; ct < 4; ct++)
      #pragma unroll
      for (int r = 0; r < 4; r++) {
        int rr = row0 + wid * 32 + mt * 16 + lg * 4 + r;
        if (rr < M)
          cs.st(rr, col0 + ct * 16 + lr, acc[mt][ct][r]);
      }
}

// ---------- logits: k2 = xo @ Wk2 (tile 128x128), epilogue: dot with q2, row-reduce, store raw logits ----------
__global__ __launch_bounds__(256) void mgemm_logits(const u16* __restrict__ xo,
                                                    const u16* __restrict__ q2,
                                                    const u16* __restrict__ Wk2t,
                                                    float* __restrict__ attn2) {
  __shared__ __align__(16) u16 Al[128][40];
  __shared__ __align__(16) u16 Bl[128][40];
  const int tid = threadIdx.x;
  const int wid = tid >> 6, lane = tid & 63;
  const int lr = lane & 15, lg = lane >> 4;
  const int wr = wid >> 1, wc = wid & 1;
  const int row0 = blockIdx.y * 128, col0 = blockIdx.x * 128;
  const int srow = tid >> 1, skh = tid & 1;
  f32x4 acc[4][4];
  #pragma unroll
  for (int i = 0; i < 4; i++)
    #pragma unroll
    for (int j = 0; j < 4; j++) acc[i][j] = (f32x4){0.f, 0.f, 0.f, 0.f};

  for (int k0 = 0; k0 < 512; k0 += 32) {
    __syncthreads();
    {
      int r = row0 + srow;
      uint4 v0 = make_uint4(0,0,0,0), v1 = make_uint4(0,0,0,0);
      if (r < 92000) {
        const u16* s = xo + (size_t)r * CC + k0 + skh * 16;
        v0 = *(const uint4*)s; v1 = *(const uint4*)(s + 8);
      }
      *(uint4*)&Al[srow][skh * 16]     = v0;
      *(uint4*)&Al[srow][skh * 16 + 8] = v1;
    }
    {
      const u16* s = Wk2t + (size_t)(col0 + srow) * 512 + k0 + skh * 16;
      *(uint4*)&Bl[srow][skh * 16]     = *(const uint4*)s;
      *(uint4*)&Bl[srow][skh * 16 + 8] = *(const uint4*)(s + 8);
    }
    __syncthreads();
    short8 afr[4], bfr[4];
    #pragma unroll
    for (int mt = 0; mt < 4; mt++)
      afr[mt] = *(const short8*)&Al[wr * 64 + mt * 16 + lr][lg * 8];
    #pragma unroll
    for (int ct = 0; ct < 4; ct++)
      bfr[ct] = *(const short8*)&Bl[wc * 64 + ct * 16 + lr][lg * 8];
    #pragma unroll
    for (int mt = 0; mt < 4; mt++)
      #pragma unroll
      for (int ct = 0; ct < 4; ct++)
        acc[mt][ct] = __builtin_amdgcn_mfma_f32_16x16x32_bf16(afr[mt], bfr[ct], acc[mt][ct], 0, 0, 0);
  }
  // epilogue: logit[r, head] = sum_{c in head's 64} k2[r][c] * q2[r/5][c]
  const int head = blockIdx.x * 2 + wc;
  #pragma unroll
  for (int mt = 0; mt < 4; mt++) {
    float part[4] = {0.f, 0.f, 0.f, 0.f};
    #pragma unroll
    for (int r = 0; r < 4; r++) {
      int rr = row0 + wr * 64 + mt * 16 + lg * 4 + r;
      int rc = rr < 92000 ? rr : 91999;
      const u16* qrow = q2 + (size_t)(rc / 5) * CC + head * 64 + lr;
      #pragma unroll
      for (int ct = 0; ct < 4; ct++)
        part[r] = fmaf(acc[mt][ct][r], bf2f(qrow[ct * 16]), part[r]);
    }
    #pragma unroll
    for (int r = 0; r < 4; r++) {
      float v = part[r];
      v += __shfl_xor(v, 1);
      v += __shfl_xor(v, 2);
      v += __shfl_xor(v, 4);
      v += __shfl_xor(v, 8);
      int rr = row0 + wr * 64 + mt * 16 + lg * 4 + r;
      if (lr == 0 && rr < 92000) {
        int b = rr / (NN * FF), rem = rr - b * (NN * FF);
        int s = rem / FF, f = rem - s * FF;
        attn2[(((size_t)b * 8 + head) * NN + s) * FF + f] = v;
      }
    }
  }
}

// ---------- stage 1 (MFMA, 16-key chunks, double-buffered DMA, P fully in-register) ----------
// Block: 4 waves x 16 q = 64 q, one (b,f). Chunk = 16 keys.
// K LDS: [16][512] linear rows, 16B-unit swizzle unit^=(row&7) (pre-swizzled DMA source).
// V LDS: [512 ch][16 keys] as 16B units u=2*ch+half, involution u^=((u>>3)&3).
// QK^T: 16x16x32, S[key=lg*4+r][q=lr] == A-frag layout of 16x16x16 -> P stays in regs.
// PV: 32x mfma16 (16x16x16), V-frag = swizzled b64 LDS reads.
__global__ __launch_bounds__(256, 2) void stage1_mfma5(const u16* __restrict__ qg,
                                                       const u16* __restrict__ kg,
                                                       const u16* __restrict__ vt,
                                                       u16* __restrict__ xo) {
  __shared__ __align__(16) u16 KF[2][16 * 512];   // 2 x 16 KB
  __shared__ __align__(16) u16 VF[2][512 * 16];   // 2 x 16 KB
  const int tid = threadIdx.x;
  const int wid = tid >> 6, lane = tid & 63;
  const int lr = lane & 15, lg = lane >> 4;
  const int qt = blockIdx.x, f = blockIdx.y, b = blockIdx.z;
  const int q0 = qt * 64 + wid * 16;

  const u16* kbase = kg + ((size_t)b * NN + f * PP) * CC;
  const u16* vbase = vt + ((size_t)(b * FF + f)) * CC * PP;   // [c][p]

  // ---- persistent Q fragments FIRST, drained, so vmcnt counts only DMA ----
  short8 qf[16];
  {
    int qrow = q0 + lr; if (qrow > NN - 1) qrow = NN - 1;
    const u16* qb = qg + ((size_t)b * NN + qrow) * CC + lg * 8;
    #pragma unroll
    for (int ck = 0; ck < 16; ck++) qf[ck] = *(const short8*)(qb + ck * 32);
  }
  asm volatile("s_waitcnt vmcnt(0)" ::: "memory");

  // ---- staging helpers (4 K-loads + 4 V-loads per wave per chunk) ----
  #define STAGE_KV(buf, kk0v)                                                  \
    {                                                                          \
      const int kk0_ = (kk0v);                                                 \
      _Pragma("unroll")                                                        \
      for (int c = 0; c < 4; c++) {                                            \
        int r = wid * 4 + c;                                                   \
        int key = kk0_ + r; if (key > PP - 1) key = PP - 1;                    \
        const u16* src = kbase + (size_t)key * CC + ((lane ^ (r & 7)) * 8);    \
        gload16(src, &KF[buf][r * 512]);                                       \
      }                                                                        \
      _Pragma("unroll")                                                        \
      for (int c = 0; c < 4; c++) {                                            \
        int j = wid * 4 + c;                                                   \
        int ulin = j * 64 + lane;                                              \
        int uc = ulin ^ ((ulin >> 3) & 3);                                     \
        int chn = uc >> 1, hh = uc & 1;                                        \
        int kidx = kk0_ + hh * 8; if (kidx > PP - 8) kidx = PP - 8;            \
        const u16* src = vbase + (size_t)chn * PP + kidx;                      \
        gload16(src, &VF[buf][j * 512]);                                       \
      }                                                                        \
    }

  // prologue: stage chunk 0 into buffer 0
  STAGE_KV(0, 0)

  f32x4 acc[32];
  #pragma unroll
  for (int j = 0; j < 32; j++) acc[j] = (f32x4){0.f, 0.f, 0.f, 0.f};
  float m = 0.f, l = 0.f;

  // per-lane constant V-read base (u16 index)
  const int vrd = (((2 * lr + (lg >> 1)) ^ (lr >> 2)) * 8) + (lg & 1) * 4;

  for (int ch = 0; ch < 58; ch++) {          // 920 = 57*16 + 8
    const int kk0 = ch * 16;
    const int nv = (ch == 57) ? 8 : 16;
    const int cur = ch & 1, nxt = cur ^ 1;
    if (ch < 57) {
      STAGE_KV(nxt, kk0 + 16)
      asm volatile("s_waitcnt vmcnt(8)" ::: "memory");   // cur buffer complete
    } else {
      asm volatile("s_waitcnt vmcnt(0)" ::: "memory");
    }
    __builtin_amdgcn_s_barrier();
    __builtin_amdgcn_sched_barrier(0);
    const u16* Kb = &KF[cur][0];
    const u16* Vb = &VF[cur][0];
    // ---- QK^T: 16 MFMAs (16x16x32), K as A from LDS (swizzled) ----
    f32x4 s0 = (f32x4){0.f, 0.f, 0.f, 0.f};
    #pragma unroll
    for (int ck = 0; ck < 16; ck++) {
      int sl0 = ((lr * 64 + ck * 4 + lg) ^ (lr & 7)) * 8;
      short8 k0 = *(const short8*)&Kb[sl0];
      s0 = __builtin_amdgcn_mfma_f32_16x16x32_bf16(k0, qf[ck], s0, 0, 0, 0);
    }
    // lane: S[key=lg*4+r][q=lr] in s0[r]
    float pmax = -1e30f;
    #pragma unroll
    for (int r = 0; r < 4; r++) {
      s0[r] *= 0.125f;
      if (lg * 4 + r < nv) pmax = fmaxf(pmax, s0[r]);
    }
    pmax = fmaxf(pmax, __shfl_xor(pmax, 16));
    pmax = fmaxf(pmax, __shfl_xor(pmax, 32));          // row max (per q=lr)
    if (__any(pmax - m > 8.f)) {                       // deferred rescale (rare)
      float mnew = fmaxf(m, pmax);
      float rs = __expf(m - mnew);
      float rsr[4];
      #pragma unroll
      for (int r = 0; r < 4; r++) rsr[r] = __shfl(rs, lg * 4 + r);
      #pragma unroll
      for (int j = 0; j < 32; j++)
        #pragma unroll
        for (int r = 0; r < 4; r++) acc[j][r] *= rsr[r];
      l *= rs;
      m = mnew;
    }
    // ---- P = exp(S - m), in-register A-frag for 16x16x16 ----
    float p0 = (lg * 4 + 0 < nv) ? __expf(s0[0] - m) : 0.f;
    float p1 = (lg * 4 + 1 < nv) ? __expf(s0[1] - m) : 0.f;
    float p2 = (lg * 4 + 2 < nv) ? __expf(s0[2] - m) : 0.f;
    float p3 = (lg * 4 + 3 < nv) ? __expf(s0[3] - m) : 0.f;
    float psum = p0 + p1 + p2 + p3;
    psum += __shfl_xor(psum, 16);
    psum += __shfl_xor(psum, 32);
    l += psum;
    u32 pw[2] = { pack2(p0, p1), pack2(p2, p3) };
    s16x4 pf = *(const s16x4*)pw;
    // ---- PV: 32 MFMAs (16x16x16), V-frag b64 from swizzled LDS ----
    #pragma unroll
    for (int ct = 0; ct < 32; ct++) {
      s16x4 vf = *(const s16x4*)&Vb[ct * 256 + vrd];
      acc[ct] = mfma16(pf, vf, acc[ct]);
    }
    __builtin_amdgcn_s_barrier();            // all waves done reading cur
  }
  // cover MFMA-write -> VALU-read hazard before epilogue (inline-asm path)
  asm volatile("s_nop 7\n\ts_nop 7" :::);
  // ---- epilogue: normalize by l, store ----
  float linv = 1.f / l;
  float li[4];
  #pragma unroll
  for (int r = 0; r < 4; r++) li[r] = __shfl(linv, lg * 4 + r);
  #pragma unroll
  for (int ct = 0; ct < 32; ct++) {
    #pragma unroll
    for (int r = 0; r < 4; r++) {
      int q = q0 + lg * 4 + r;
      if (q < NN)
        xo[((size_t)(b * NN + q) * FF + f) * CC + ct * 16 + lr] = f2bf(acc[ct][r] * li[r]);
    }
  }
  #undef STAGE_KV
}

// ---------- softmax over F=5, in place on attn2 ----------
__global__ __launch_bounds__(256) void softmax_f5(float* __restrict__ a) {
  int t = blockIdx.x * 256 + threadIdx.x;
  if (t >= NB * 8 * NN) return;
  float* p = a + (size_t)t * FF;
  float l0 = p[0], l1 = p[1], l2 = p[2], l3 = p[3], l4 = p[4];
  float m = fmaxf(fmaxf(fmaxf(l0, l1), fmaxf(l2, l3)), l4);
  float e0 = __expf(l0 - m), e1 = __expf(l1 - m), e2 = __expf(l2 - m),
        e3 = __expf(l3 - m), e4 = __expf(l4 - m);
  float inv = 1.f / (e0 + e1 + e2 + e3 + e4);
  p[0] = e0 * inv; p[1] = e1 * inv; p[2] = e2 * inv; p[3] = e3 * inv; p[4] = e4 * inv;
}

// ---------- sentinel ----------
__global__ void sentinel_fill(float* o) { o[threadIdx.x] = 777.0f; }

// ---------- launcher ----------
extern "C" void kernel_launch(void* const* d_in, const int* in_sizes, int n_in,
                              void* d_out, int out_size, void* d_ws, size_t ws_size,
                              hipStream_t stream) {
  const float* x     = (const float*)d_in[0];
  const float* Wqkv  = (const float*)d_in[1];
  const float* Wq2   = (const float*)d_in[2];
  const float* Wkv2  = (const float*)d_in[3];
  const float* Wproj = (const float*)d_in[4];
  const float* bproj = (const float*)d_in[5];
  float* out   = (float*)d_out;
  float* attn2 = out + (size_t)PP * NB * FF * CC;

  char* ws = (char*)d_ws;
  const size_t SZ = (size_t)18400 * CC * 2;          // 18.8 MB
  const size_t XO = (size_t)92000 * CC * 2;          // 94.2 MB
  const size_t WT = (size_t)(1536 + 512 + 1024 + 512) * 512 * 2;  // 3.67 MB
  const size_t NEED = 3 * SZ + XO + WT;              // ~154.4 MB
  if (ws_size < NEED) {
    sentinel_fill<<<1, 256, 0, stream>>>(out);
    return;
  }
  u16* q    = (u16*)(ws);
  u16* k    = (u16*)(ws + SZ);
  u16* vt   = (u16*)(ws + 2 * SZ);
  u16* xo   = (u16*)(ws + 3 * SZ);
  u16* wt_qkv  = (u16*)(ws + 3 * SZ + XO);
  u16* wt_q2   = wt_qkv + (size_t)1536 * 512;
  u16* wt_kv2  = wt_q2  + (size_t)512 * 512;
  u16* wt_proj = wt_kv2 + (size_t)1024 * 512;
  u16* q2   = (u16*)(ws);            // alias q (dead after stage1)
  u16* outp = (u16*)(ws + SZ);       // alias k (dead after stage1)

  // 0) weight transpose + bf16 conversion
  wtrans<<<dim3(48, 16), 256, 0, stream>>>(Wqkv,  wt_qkv,  1536);
  wtrans<<<dim3(16, 16), 256, 0, stream>>>(Wq2,   wt_q2,   512);
  wtrans<<<dim3(32, 16), 256, 0, stream>>>(Wkv2,  wt_kv2,  1024);
  wtrans<<<dim3(16, 16), 256, 0, stream>>>(Wproj, wt_proj, 512);

  // 1) QKV projection (MFMA; v written transposed per (b,f))
  {
    AProvX ap{x}; CSinkQKV cs{q, k, vt};
    mgemm128<<<dim3(12, 144), 256, 0, stream>>>(ap, wt_qkv, cs, 18400);
  }
  // 2) stage-1 space attention (MFMA, 16-key dbuf pipeline) -> xo (B,N,F,C)
  stage1_mfma5<<<dim3(72, 5, 4), 256, 0, stream>>>(q, k, vt, xo);
  // 3) q2 = diag(xo) @ W_q2 * scale   (overwrites q region)
  {
    AProvDiag ap{xo}; CSinkQ2 cs{q2};
    mgemm128<<<dim3(4, 144), 256, 0, stream>>>(ap, wt_q2, cs, 18400);
  }
  // 4) fused k2-GEMM + q2 dot -> raw logits into attn2 slice of d_out
  mgemm_logits<<<dim3(4, 719), 256, 0, stream>>>(xo, q2, wt_kv2, attn2);
  // 5) softmax over F in place
  softmax_f5<<<(NB * 8 * NN + 255) / 256, 256, 0, stream>>>(attn2);
  // 6) fused mix + W_v2 -> out_pre (overwrites k region); BN=64, head = blockIdx.x
  {
    AProvMix ap{xo, attn2}; CSinkBF512 cs{outp};
    mgemm64<<<dim3(8, 144), 256, 0, stream>>>(ap, wt_kv2 + (size_t)512 * 512, cs, 18400);
  }
  // 7) final projection + bias + permute to (P, B*F, C)
  {
    AProvBF ap{outp, 18400}; CSinkProj cs{out, bproj};
    mgemm128<<<dim3(4, 144), 256, 0, stream>>>(ap, wt_proj, cs, 18400);
  }
}